// Round 11
// baseline (499.842 us; speedup 1.0000x reference)
//
#include <hip/hip_runtime.h>
#include <hip/hip_bf16.h>

typedef short short8 __attribute__((ext_vector_type(8)));
typedef float f32x4 __attribute__((ext_vector_type(4)));

__device__ __forceinline__ float lrelu(float x, float s) { return x > 0.f ? x : x * s; }

__device__ __forceinline__ unsigned short f2bf(float x) {
  union { __hip_bfloat16 b; unsigned short u; } cv;
  cv.b = __float2bfloat16(x);
  return cv.u;
}
__device__ __forceinline__ float bf2f(unsigned short u) {
  return __uint_as_float(((unsigned int)u) << 16);
}

// ---------------- unified param prep ----------------
__global__ void __launch_bounds__(256)
prep_kernel(const float* __restrict__ g, unsigned short* __restrict__ gt,
            const float* __restrict__ W1, const float* __restrict__ as1,
            const float* __restrict__ ad1, unsigned short* __restrict__ wt1,
            unsigned short* __restrict__ vt1,
            const float* __restrict__ W2, const float* __restrict__ as2,
            const float* __restrict__ ad2, unsigned short* __restrict__ wt2,
            unsigned short* __restrict__ vt2)
{
  __shared__ float ts[32][68];
  __shared__ float ss[2][128], sd[2][128];
  const int b = blockIdx.x;
  const int t = threadIdx.x;
  if (b < 32) {
    const int kb = (b >> 3) * 32;
    const int cb = (b & 7) * 64;
    {
      const int r = t >> 3;
      const int c = (t & 7) * 8;
      float4 v0 = *(const float4*)&g[(size_t)(kb + r) * 512 + cb + c];
      float4 v1 = *(const float4*)&g[(size_t)(kb + r) * 512 + cb + c + 4];
      *(float4*)&ts[r][c] = v0;
      *(float4*)&ts[r][c + 4] = v1;
    }
    __syncthreads();
    {
      const int c = t >> 2;
      const int k0 = (t & 3) * 8;
      unsigned short pk[8];
      #pragma unroll
      for (int j = 0; j < 8; ++j) pk[j] = f2bf(ts[k0 + j][c]);
      *(short8*)&gt[(size_t)(cb + c) * 128 + kb + k0] = *(short8*)pk;
    }
  } else {
    const int isW2 = (b >= 96) ? 1 : 0;
    const float* W  = isW2 ? W2 : W1;
    const float* as = isW2 ? as2 : as1;
    const float* ad = isW2 ? ad2 : ad1;
    unsigned short* wt = isW2 ? wt2 : wt1;
    unsigned short* vt = isW2 ? vt2 : vt1;
    const int HEADS = isW2 ? 1 : 8;
    const int kk = t >> 7;
    const int c  = t & 127;
    const int k  = ((b - (isW2 ? 96 : 32)) << 1) + kk;
    const float wv = W[k * 128 + c];
    wt[c * 128 + k] = f2bf(wv);
    ss[kk][c] = wv * as[c];
    sd[kk][c] = wv * ad[c];
    __syncthreads();
    if (c < 16) {
      const int C = 128 / HEADS;
      const int h = (c < 8) ? c : c - 8;
      float s = 0.f;
      if (h < HEADS) {
        const float* sb = (c < 8) ? ss[kk] : sd[kk];
        for (int j = 0; j < C; ++j) s += sb[h * C + j];
      }
      vt[c * 128 + k] = f2bf(s);
    }
  }
}

// ---------------- CSR build ----------------
__global__ void __launch_bounds__(256)
deg_count_kernel(const int* __restrict__ edst, int* __restrict__ deg, int E, int n) {
  const int grp = blockIdx.x & 3;
  const int lo = (int)(((long long)n * grp) >> 2);
  const int hi = (int)(((long long)n * (grp + 1)) >> 2);
  const int tid = (blockIdx.x >> 2) * blockDim.x + threadIdx.x;
  const int stride = (gridDim.x >> 2) * blockDim.x;
  for (int i = tid; i < E; i += stride) {
    const int d = edst[i];
    if (d >= lo && d < hi) atomicAdd(&deg[d], 1);
  }
}

__global__ void __launch_bounds__(256)
scan1_kernel(const int* __restrict__ deg, int* __restrict__ out,
             int* __restrict__ blksum, int n) {
  __shared__ int ts[256];
  const int t = threadIdx.x;
  const int base = blockIdx.x * 2048 + t * 8;
  int v[8]; int s = 0;
  #pragma unroll
  for (int i = 0; i < 8; ++i) {
    int x = (base + i < n) ? deg[base + i] + 1 : 0;   // +1 = self-loop
    v[i] = s; s += x;
  }
  ts[t] = s;
  __syncthreads();
  for (int off = 1; off < 256; off <<= 1) {
    int add = (t >= off) ? ts[t - off] : 0;
    __syncthreads();
    ts[t] += add;
    __syncthreads();
  }
  const int excl = ts[t] - s;
  #pragma unroll
  for (int i = 0; i < 8; ++i)
    if (base + i < n) out[base + i] = excl + v[i];
  if (t == 255) blksum[blockIdx.x] = ts[255];
}

__global__ void scan2_kernel(int* __restrict__ blksum, int nb) {
  const int t = threadIdx.x;
  int v = (t < nb) ? blksum[t] : 0;
  #pragma unroll
  for (int off = 1; off < 64; off <<= 1) {
    int u = __shfl_up(v, off);
    if (t >= off) v += u;
  }
  if (t < nb) blksum[t] = v;
}

__global__ void scan3_kernel(int* __restrict__ out, const int* __restrict__ blksum, int n) {
  int i = blockIdx.x * blockDim.x + threadIdx.x;
  if (i >= n) return;
  int b = i >> 11;
  if (b > 0) out[i] += blksum[b - 1];
}

__global__ void __launch_bounds__(256)
scatter_kernel(const int* __restrict__ esrc, const int* __restrict__ edst,
               int* __restrict__ rowptr, int* __restrict__ col,
               int E, int n) {
  const int grp = blockIdx.x & 3;
  const int lo = (int)(((long long)n * grp) >> 2);
  const int hi = (int)(((long long)n * (grp + 1)) >> 2);
  const int tid = (blockIdx.x >> 2) * blockDim.x + threadIdx.x;
  const int stride = (gridDim.x >> 2) * blockDim.x;
  const int Etot = E + n;
  for (int i = tid; i < Etot; i += stride) {
    int s, d;
    if (i < E) { s = esrc[i]; d = edst[i]; } else { s = d = i - E; }
    if (d >= lo && d < hi) {
      int p = atomicAdd(&rowptr[d], 1);
      col[p] = s;
    }
  }
}

// ---------------- features + attention dots (bf16 MFMA) ----------------
template<int HEADS, bool BF16IN>
__global__ void __launch_bounds__(256)
feat_mfma_kernel(const void* __restrict__ In_, const unsigned short* __restrict__ wt,
                 const unsigned short* __restrict__ vt, const float* __restrict__ bias_in,
                 unsigned short* __restrict__ Hout, float* __restrict__ a_src,
                 float* __restrict__ a_dst, int n)
{
  __shared__ unsigned short xs[64][136];
  const int t = threadIdx.x;
  const int w = t >> 6, lane = t & 63;
  const int l15 = lane & 15, lg = lane >> 4;
  const int nbase = blockIdx.x << 6;

  {
    const int r = t >> 2;
    const int c0s = (t & 3) << 5;
    const int node = nbase + r;
    if (BF16IN) {
      const unsigned short* In2 = (const unsigned short*)In_;
      #pragma unroll
      for (int i = 0; i < 4; ++i) {
        unsigned short pk[8];
        if (node < n) {
          short8 v = *(const short8*)&In2[(size_t)node * 128 + c0s + i * 8];
          #pragma unroll
          for (int j = 0; j < 8; ++j) {
            float f = bf2f((unsigned short)v[j]) + bias_in[c0s + i * 8 + j];
            pk[j] = f2bf(lrelu(f, 0.01f));
          }
        } else {
          #pragma unroll
          for (int j = 0; j < 8; ++j) pk[j] = 0;
        }
        *(short8*)&xs[r][c0s + i * 8] = *(short8*)pk;
      }
    } else {
      const float* In1 = (const float*)In_;
      #pragma unroll
      for (int i = 0; i < 8; ++i) {
        unsigned short pk[4];
        if (node < n) {
          float4 v = *(const float4*)&In1[(size_t)node * 128 + c0s + i * 4];
          pk[0] = f2bf(v.x); pk[1] = f2bf(v.y); pk[2] = f2bf(v.z); pk[3] = f2bf(v.w);
        } else { pk[0] = pk[1] = pk[2] = pk[3] = 0; }
        *(uint2*)&xs[r][c0s + i * 4] = *(uint2*)pk;
      }
    }
  }
  __syncthreads();

  short8 afr[4];
  #pragma unroll
  for (int kc = 0; kc < 4; ++kc)
    afr[kc] = *(const short8*)&xs[w * 16 + l15][kc * 32 + lg * 8];

  const unsigned short* bp[9];
  #pragma unroll
  for (int ct = 0; ct < 8; ++ct)
    bp[ct] = wt + (size_t)(ct * 16 + l15) * 128 + lg * 8;
  bp[8] = vt + (size_t)l15 * 128 + lg * 8;

  f32x4 acc[9];
  #pragma unroll
  for (int ct = 0; ct < 9; ++ct) acc[ct] = (f32x4){0.f, 0.f, 0.f, 0.f};

  short8 bcur[9], bnxt[9];
  #pragma unroll
  for (int ct = 0; ct < 9; ++ct) bcur[ct] = *(const short8*)bp[ct];

  #pragma unroll
  for (int kc = 0; kc < 4; ++kc) {
    if (kc < 3) {
      #pragma unroll
      for (int ct = 0; ct < 9; ++ct)
        bnxt[ct] = *(const short8*)(bp[ct] + (kc + 1) * 32);
    }
    #pragma unroll
    for (int ct = 0; ct < 9; ++ct)
      acc[ct] = __builtin_amdgcn_mfma_f32_16x16x32_bf16(afr[kc], bcur[ct], acc[ct], 0, 0, 0);
    if (kc < 3) {
      #pragma unroll
      for (int ct = 0; ct < 9; ++ct) bcur[ct] = bnxt[ct];
    }
  }
  __syncthreads();

  #pragma unroll
  for (int ct = 0; ct < 8; ++ct)
    #pragma unroll
    for (int r = 0; r < 4; ++r)
      xs[w * 16 + lg * 4 + r][ct * 16 + l15] = f2bf(acc[ct][r]);
  __syncthreads();

  {
    const int r = t >> 2;
    const int c0s = (t & 3) << 5;
    const int node = nbase + r;
    if (node < n) {
      #pragma unroll
      for (int i = 0; i < 4; ++i)
        *(short8*)&Hout[(size_t)node * 128 + c0s + i * 8] = *(const short8*)&xs[r][c0s + i * 8];
    }
  }
  #pragma unroll
  for (int r = 0; r < 4; ++r) {
    const int node = nbase + w * 16 + lg * 4 + r;
    if (node < n) {
      const float v = acc[8][r];
      if (HEADS == 8) {
        if (l15 < 8) a_src[node * 8 + l15] = v;
        else         a_dst[node * 8 + (l15 - 8)] = v;
      } else {
        if (l15 == 0) a_src[node] = v;
        else if (l15 == 8) a_dst[node] = v;
      }
    }
  }
}

// ---------------- CSR gather-aggregate (single-pass softmax, 16 gathers in flight) ----------------
template<int HEADS>
__global__ void __launch_bounds__(256)
agg_csr_kernel(const int* __restrict__ rowptr_end, const int* __restrict__ col,
               const float* __restrict__ a_src, const float* __restrict__ a_dst,
               const unsigned short* __restrict__ Hf, unsigned int* __restrict__ agg, int n)
{
  const int wave = threadIdx.x >> 6;
  const int lane = threadIdx.x & 63;
  const int d = blockIdx.x * 4 + wave;
  if (d >= n) return;
  const int beg = (d == 0) ? 0 : rowptr_end[d - 1];
  const int end = rowptr_end[d];

  const int ei = lane >> 3;
  const int hh = (HEADS == 8) ? (lane & 7) : 0;
  const int bh = (HEADS == 8) ? (lane >> 3) : 0;
  const float adv = (HEADS == 8) ? a_dst[d * 8 + hh] : a_dst[d];
  const unsigned int* Hu = (const unsigned int*)Hf;

  float accx = 0.f, accy = 0.f, sum = 0.f;
  const int nb16 = (end - beg) >> 4;
  int sv0 = 0, sv1 = 0; float a0 = 0.f, a1 = 0.f;
  if (nb16 > 0) {
    sv0 = col[beg + ei];
    sv1 = col[beg + 8 + ei];
    a0 = __expf(lrelu(a_src[sv0 * HEADS + hh] + adv, 0.2f));
    a1 = __expf(lrelu(a_src[sv1 * HEADS + hh] + adv, 0.2f));
    if (HEADS == 8 || (lane & 7) == 0) sum += a0 + a1;
  }
  for (int b = 0; b < nb16; ++b) {
    // addresses for 16 gathers
    int s[16];
    #pragma unroll
    for (int e = 0; e < 8; ++e) {
      s[e]     = __shfl(sv0, e * 8);
      s[8 + e] = __shfl(sv1, e * 8);
    }
    const float a0o = a0, a1o = a1;
    unsigned int hv[16];
    #pragma unroll
    for (int e = 0; e < 16; ++e) hv[e] = Hu[(size_t)s[e] * 64 + lane];
    if (b + 1 < nb16) {   // prefetch next batch's col+exp under the gather latency
      const int p = beg + ((b + 1) << 4);
      sv0 = col[p + ei];
      sv1 = col[p + 8 + ei];
      a0 = __expf(lrelu(a_src[sv0 * HEADS + hh] + adv, 0.2f));
      a1 = __expf(lrelu(a_src[sv1 * HEADS + hh] + adv, 0.2f));
      if (HEADS == 8 || (lane & 7) == 0) sum += a0 + a1;
    }
    #pragma unroll
    for (int e = 0; e < 8; ++e) {
      const float alv = __shfl(a0o, e * 8 + bh);
      accx += alv * __uint_as_float(hv[e] << 16);
      accy += alv * __uint_as_float(hv[e] & 0xffff0000u);
    }
    #pragma unroll
    for (int e = 0; e < 8; ++e) {
      const float alv = __shfl(a1o, e * 8 + bh);
      accx += alv * __uint_as_float(hv[8 + e] << 16);
      accy += alv * __uint_as_float(hv[8 + e] & 0xffff0000u);
    }
  }
  int p0 = beg + (nb16 << 4);
  if (p0 + 8 <= end) {   // one 8-batch
    const int sv = col[p0 + ei];
    const float a = __expf(lrelu(a_src[sv * HEADS + hh] + adv, 0.2f));
    if (HEADS == 8 || (lane & 7) == 0) sum += a;
    int s[8];
    #pragma unroll
    for (int e = 0; e < 8; ++e) s[e] = __shfl(sv, e * 8);
    unsigned int hv[8];
    #pragma unroll
    for (int e = 0; e < 8; ++e) hv[e] = Hu[(size_t)s[e] * 64 + lane];
    #pragma unroll
    for (int e = 0; e < 8; ++e) {
      const float alv = __shfl(a, e * 8 + bh);
      accx += alv * __uint_as_float(hv[e] << 16);
      accy += alv * __uint_as_float(hv[e] & 0xffff0000u);
    }
    p0 += 8;
  }
  if (p0 < end) {   // scalar tail < 8
    const int cnt = end - p0;
    int svt = 0; float at = 0.f;
    if (ei < cnt) {
      svt = col[p0 + ei];
      at = __expf(lrelu(a_src[svt * HEADS + hh] + adv, 0.2f));
      if (HEADS == 8 || (lane & 7) == 0) sum += at;
    }
    for (int e = 0; e < cnt; ++e) {
      const float alv = __shfl(at, e * 8 + bh);
      const int   sx  = __shfl(svt, e * 8);
      const unsigned int hv = Hu[(size_t)sx * 64 + lane];
      accx += alv * __uint_as_float(hv << 16);
      accy += alv * __uint_as_float(hv & 0xffff0000u);
    }
  }
  sum += __shfl_xor(sum, 8);
  sum += __shfl_xor(sum, 16);
  sum += __shfl_xor(sum, 32);
  const float denom = __shfl(sum, bh) + 1e-16f;
  const float inv = 1.f / denom;
  agg[(size_t)d * 64 + lane] = (unsigned int)f2bf(accx * inv) | ((unsigned int)f2bf(accy * inv) << 16);
}

// ---------------- h@g + cosine vs mu (bf16 MFMA, 32-node tiles — round-7 structure) ----------------
__global__ void __launch_bounds__(256)
final_kernel(const unsigned short* __restrict__ agg2b, const float* __restrict__ b2,
             const unsigned short* __restrict__ gt, const float* __restrict__ mu,
             float* __restrict__ outp, int n)
{
  __shared__ unsigned short os[32][136];
  const int t = threadIdx.x;
  const int w = t >> 6;
  const int lane = t & 63;
  const int l15 = lane & 15;
  const int lg = lane >> 4;
  const int nbase = blockIdx.x << 5;

  {
    const int r = t >> 3;
    const int c = (t & 7) * 16;
    const int node = nbase + r;
    unsigned short pk[16];
    if (node < n) {
      short8 v0 = *(const short8*)&agg2b[(size_t)node * 128 + c];
      short8 v1 = *(const short8*)&agg2b[(size_t)node * 128 + c + 8];
      #pragma unroll
      for (int j = 0; j < 8; ++j) pk[j]     = f2bf(bf2f((unsigned short)v0[j]) + b2[c + j]);
      #pragma unroll
      for (int j = 0; j < 8; ++j) pk[8 + j] = f2bf(bf2f((unsigned short)v1[j]) + b2[c + 8 + j]);
    } else {
      #pragma unroll
      for (int i = 0; i < 16; ++i) pk[i] = 0;
    }
    *(short8*)&os[r][c]     = *(short8*)&pk[0];
    *(short8*)&os[r][c + 8] = *(short8*)&pk[8];
  }
  __syncthreads();

  short8 afr[2][4];
  #pragma unroll
  for (int rt = 0; rt < 2; ++rt)
    #pragma unroll
    for (int kc = 0; kc < 4; ++kc)
      afr[rt][kc] = *(const short8*)&os[rt * 16 + l15][kc * 32 + lg * 8];

  const unsigned short* gw = gt + (size_t)(w * 128 + l15) * 128 + lg * 8;

  f32x4 acc[2][8];
  #pragma unroll
  for (int rt = 0; rt < 2; ++rt)
    #pragma unroll
    for (int ct = 0; ct < 8; ++ct)
      acc[rt][ct] = (f32x4){0.f, 0.f, 0.f, 0.f};

  short8 bcur[8], bnxt[8];
  #pragma unroll
  for (int ct = 0; ct < 8; ++ct)
    bcur[ct] = *(const short8*)&gw[(size_t)ct * 2048];

  #pragma unroll
  for (int kc = 0; kc < 4; ++kc) {
    if (kc < 3) {
      #pragma unroll
      for (int ct = 0; ct < 8; ++ct)
        bnxt[ct] = *(const short8*)&gw[(size_t)ct * 2048 + (kc + 1) * 32];
    }
    #pragma unroll
    for (int ct = 0; ct < 8; ++ct) {
      acc[0][ct] = __builtin_amdgcn_mfma_f32_16x16x32_bf16(afr[0][kc], bcur[ct], acc[0][ct], 0, 0, 0);
      acc[1][ct] = __builtin_amdgcn_mfma_f32_16x16x32_bf16(afr[1][kc], bcur[ct], acc[1][ct], 0, 0, 0);
    }
    if (kc < 3) {
      #pragma unroll
      for (int ct = 0; ct < 8; ++ct) bcur[ct] = bnxt[ct];
    }
  }

  #pragma unroll
  for (int kg = 0; kg < 2; ++kg) {
    const int k = w * 2 + kg;
    float muv[4];
    #pragma unroll
    for (int ct = 0; ct < 4; ++ct) muv[ct] = mu[k * 64 + ct * 16 + l15];
    float mq = 0.f;
    #pragma unroll
    for (int ct = 0; ct < 4; ++ct) mq += muv[ct] * muv[ct];
    mq += __shfl_xor(mq, 1); mq += __shfl_xor(mq, 2);
    mq += __shfl_xor(mq, 4); mq += __shfl_xor(mq, 8);
    const float mun = fmaxf(sqrtf(mq), 1e-8f);
    #pragma unroll
    for (int rt = 0; rt < 2; ++rt) {
      float num[4] = {0.f, 0.f, 0.f, 0.f};
      float ss[4]  = {0.f, 0.f, 0.f, 0.f};
      #pragma unroll
      for (int ct = 0; ct < 4; ++ct) {
        const f32x4 a = acc[rt][kg * 4 + ct];
        #pragma unroll
        for (int r = 0; r < 4; ++r) {
          num[r] += muv[ct] * a[r];
          ss[r]  += a[r] * a[r];
        }
      }
      #pragma unroll
      for (int r = 0; r < 4; ++r) {
        num[r] += __shfl_xor(num[r], 1); ss[r] += __shfl_xor(ss[r], 1);
        num[r] += __shfl_xor(num[r], 2); ss[r] += __shfl_xor(ss[r], 2);
        num[r] += __shfl_xor(num[r], 4); ss[r] += __shfl_xor(ss[r], 4);
        num[r] += __shfl_xor(num[r], 8); ss[r] += __shfl_xor(ss[r], 8);
      }
      if (l15 == 0) {
        #pragma unroll
        for (int r = 0; r < 4; ++r) {
          const int node = nbase + rt * 16 + lg * 4 + r;
          if (node < n) {
            const float den = mun * fmaxf(sqrtf(ss[r]), 1e-8f);
            outp[(size_t)node * 8 + k] = num[r] / den;
          }
        }
      }
    }
  }
}

extern "C" void kernel_launch(void* const* d_in, const int* in_sizes, int n_in,
                              void* d_out, int out_size, void* d_ws, size_t ws_size,
                              hipStream_t stream)
{
  const float* x   = (const float*)d_in[0];
  const int*   eix = (const int*)d_in[1];
  const float* W1  = (const float*)d_in[2];
  const float* as1 = (const float*)d_in[3];
  const float* ad1 = (const float*)d_in[4];
  const float* b1  = (const float*)d_in[5];
  const float* W2  = (const float*)d_in[6];
  const float* as2 = (const float*)d_in[7];
  const float* ad2 = (const float*)d_in[8];
  const float* b2  = (const float*)d_in[9];
  const float* g   = (const float*)d_in[10];
  const float* mu  = (const float*)d_in[11];
  float* outp = (float*)d_out;

  const int n    = in_sizes[0] / 128;
  const int E    = in_sizes[1] / 2;
  const int* esrc = eix;
  const int* edst = eix + E;

  unsigned short* hb  = (unsigned short*)d_ws;
  unsigned short* gt  = hb + (size_t)n * 128;
  unsigned short* wt1 = gt + 512 * 128;
  unsigned short* vt1 = wt1 + 128 * 128;
  unsigned short* wt2 = vt1 + 16 * 128;
  unsigned short* vt2 = wt2 + 128 * 128;
  unsigned short* agg_b = (unsigned short*)((char*)d_ws + (size_t)n * 512);
  float* asrc   = (float*)((char*)d_ws + (size_t)n * 1024);
  float* adst   = asrc + (size_t)n * 8;
  int*   rowptr = (int*)(adst + (size_t)n * 8);
  int*   col    = rowptr + n;
  int*   deg    = (int*)agg_b;
  int*   blksum = deg + n;

  // ---------------- param prep (fused) ----------------
  prep_kernel<<<160, 256, 0, stream>>>(g, gt, W1, as1, ad1, wt1, vt1, W2, as2, ad2, wt2, vt2);

  // ---------------- CSR build (by destination, self-loops included) ----------------
  const int nb = (n + 2047) / 2048;
  hipMemsetAsync(deg, 0, (size_t)n * sizeof(int), stream);
  deg_count_kernel<<<2048, 256, 0, stream>>>(edst, deg, E, n);
  scan1_kernel<<<nb, 256, 0, stream>>>(deg, rowptr, blksum, n);
  scan2_kernel<<<1, 64, 0, stream>>>(blksum, nb);
  scan3_kernel<<<(n + 255) / 256, 256, 0, stream>>>(rowptr, blksum, n);
  scatter_kernel<<<2048, 256, 0, stream>>>(esrc, edst, rowptr, col, E, n);

  // ---------------- conv1 (heads=8, C=16) ----------------
  feat_mfma_kernel<8, false><<<(n + 63) / 64, 256, 0, stream>>>(
      x, wt1, vt1, nullptr, hb, asrc, adst, n);
  agg_csr_kernel<8><<<(n + 3) / 4, 256, 0, stream>>>(
      rowptr, col, asrc, adst, hb, (unsigned int*)agg_b, n);

  // ---------------- conv2 (heads=1, C=128) ----------------
  feat_mfma_kernel<1, true><<<(n + 63) / 64, 256, 0, stream>>>(
      agg_b, wt2, vt2, b1, hb, asrc, adst, n);
  agg_csr_kernel<1><<<(n + 3) / 4, 256, 0, stream>>>(
      rowptr, col, asrc, adst, hb, (unsigned int*)agg_b, n);

  // ---------------- h@g + cosine vs mu ----------------
  final_kernel<<<(n + 31) / 32, 256, 0, stream>>>(agg_b, b2, gt, mu, outp, n);
}

// Round 12
// 492.952 us; speedup vs baseline: 1.0140x; 1.0140x over previous
//
#include <hip/hip_runtime.h>
#include <hip/hip_bf16.h>

typedef short short8 __attribute__((ext_vector_type(8)));
typedef float f32x4 __attribute__((ext_vector_type(4)));

__device__ __forceinline__ float lrelu(float x, float s) { return x > 0.f ? x : x * s; }

__device__ __forceinline__ unsigned short f2bf(float x) {
  union { __hip_bfloat16 b; unsigned short u; } cv;
  cv.b = __float2bfloat16(x);
  return cv.u;
}
__device__ __forceinline__ float bf2f(unsigned short u) {
  return __uint_as_float(((unsigned int)u) << 16);
}

// ---------------- unified param prep ----------------
// blocks 0..31: g -> gt ; 32..95: W1 ; 96..159: W2 ; 160: gm' = (g contracted with mu)/||mu_k||
__global__ void __launch_bounds__(256)
prep_kernel(const float* __restrict__ g, unsigned short* __restrict__ gt,
            const float* __restrict__ W1, const float* __restrict__ as1,
            const float* __restrict__ ad1, unsigned short* __restrict__ wt1,
            unsigned short* __restrict__ vt1,
            const float* __restrict__ W2, const float* __restrict__ as2,
            const float* __restrict__ ad2, unsigned short* __restrict__ wt2,
            unsigned short* __restrict__ vt2,
            const float* __restrict__ mu, unsigned short* __restrict__ gmt)
{
  __shared__ float ts[32][68];
  __shared__ float ss[2][128], sd[2][128];
  __shared__ float msq[8];
  const int b = blockIdx.x;
  const int t = threadIdx.x;
  if (b < 32) {
    const int kb = (b >> 3) * 32;
    const int cb = (b & 7) * 64;
    {
      const int r = t >> 3;
      const int c = (t & 7) * 8;
      float4 v0 = *(const float4*)&g[(size_t)(kb + r) * 512 + cb + c];
      float4 v1 = *(const float4*)&g[(size_t)(kb + r) * 512 + cb + c + 4];
      *(float4*)&ts[r][c] = v0;
      *(float4*)&ts[r][c + 4] = v1;
    }
    __syncthreads();
    {
      const int c = t >> 2;
      const int k0 = (t & 3) * 8;
      unsigned short pk[8];
      #pragma unroll
      for (int j = 0; j < 8; ++j) pk[j] = f2bf(ts[k0 + j][c]);
      *(short8*)&gt[(size_t)(cb + c) * 128 + kb + k0] = *(short8*)pk;
    }
  } else if (b < 160) {
    const int isW2 = (b >= 96) ? 1 : 0;
    const float* W  = isW2 ? W2 : W1;
    const float* as = isW2 ? as2 : as1;
    const float* ad = isW2 ? ad2 : ad1;
    unsigned short* wt = isW2 ? wt2 : wt1;
    unsigned short* vt = isW2 ? vt2 : vt1;
    const int HEADS = isW2 ? 1 : 8;
    const int kk = t >> 7;
    const int c  = t & 127;
    const int k  = ((b - (isW2 ? 96 : 32)) << 1) + kk;
    const float wv = W[k * 128 + c];
    wt[c * 128 + k] = f2bf(wv);
    ss[kk][c] = wv * as[c];
    sd[kk][c] = wv * ad[c];
    __syncthreads();
    if (c < 16) {
      const int C = 128 / HEADS;
      const int h = (c < 8) ? c : c - 8;
      float s = 0.f;
      if (h < HEADS) {
        const float* sb = (c < 8) ? ss[kk] : sd[kk];
        for (int j = 0; j < C; ++j) s += sb[h * C + j];
      }
      vt[c * 128 + k] = f2bf(s);
    }
  } else {
    // gm'[j][k] = (sum_m mu[k,m] * g[j, k*64+m]) / max(||mu_k||, eps); layout [16][128], rows 8..15 zero
    if (t < 8) {
      float s = 0.f;
      for (int m = 0; m < 64; ++m) { const float v = mu[t * 64 + m]; s += v * v; }
      msq[t] = fmaxf(sqrtf(s), 1e-8f);
    }
    __syncthreads();
    #pragma unroll
    for (int p = 0; p < 4; ++p) {
      const int idx = t + p * 256;
      const int j = idx >> 3, k = idx & 7;
      float s = 0.f;
      for (int m = 0; m < 64; ++m) s += mu[k * 64 + m] * g[(size_t)j * 512 + k * 64 + m];
      gmt[k * 128 + j] = f2bf(s / msq[k]);
      gmt[(8 + (idx >> 7)) * 128 + (idx & 127)] = 0;
    }
  }
}

// ---------------- CSR build ----------------
__global__ void __launch_bounds__(256)
deg_count_kernel(const int* __restrict__ edst, int* __restrict__ deg, int E, int n) {
  const int grp = blockIdx.x & 3;
  const int lo = (int)(((long long)n * grp) >> 2);
  const int hi = (int)(((long long)n * (grp + 1)) >> 2);
  const int tid = (blockIdx.x >> 2) * blockDim.x + threadIdx.x;
  const int stride = (gridDim.x >> 2) * blockDim.x;
  for (int i = tid; i < E; i += stride) {
    const int d = edst[i];
    if (d >= lo && d < hi) atomicAdd(&deg[d], 1);
  }
}

__global__ void __launch_bounds__(256)
scan1_kernel(const int* __restrict__ deg, int* __restrict__ out,
             int* __restrict__ blksum, int n) {
  __shared__ int ts[256];
  const int t = threadIdx.x;
  const int base = blockIdx.x * 2048 + t * 8;
  int v[8]; int s = 0;
  #pragma unroll
  for (int i = 0; i < 8; ++i) {
    int x = (base + i < n) ? deg[base + i] + 1 : 0;   // +1 = self-loop
    v[i] = s; s += x;
  }
  ts[t] = s;
  __syncthreads();
  for (int off = 1; off < 256; off <<= 1) {
    int add = (t >= off) ? ts[t - off] : 0;
    __syncthreads();
    ts[t] += add;
    __syncthreads();
  }
  const int excl = ts[t] - s;
  #pragma unroll
  for (int i = 0; i < 8; ++i)
    if (base + i < n) out[base + i] = excl + v[i];
  if (t == 255) blksum[blockIdx.x] = ts[255];
}

__global__ void scan2_kernel(int* __restrict__ blksum, int nb) {
  const int t = threadIdx.x;
  int v = (t < nb) ? blksum[t] : 0;
  #pragma unroll
  for (int off = 1; off < 64; off <<= 1) {
    int u = __shfl_up(v, off);
    if (t >= off) v += u;
  }
  if (t < nb) blksum[t] = v;
}

__global__ void scan3_kernel(int* __restrict__ out, const int* __restrict__ blksum, int n) {
  int i = blockIdx.x * blockDim.x + threadIdx.x;
  if (i >= n) return;
  int b = i >> 11;
  if (b > 0) out[i] += blksum[b - 1];
}

__global__ void __launch_bounds__(256)
scatter_kernel(const int* __restrict__ esrc, const int* __restrict__ edst,
               int* __restrict__ rowptr, int* __restrict__ col,
               int E, int n) {
  const int grp = blockIdx.x & 3;
  const int lo = (int)(((long long)n * grp) >> 2);
  const int hi = (int)(((long long)n * (grp + 1)) >> 2);
  const int tid = (blockIdx.x >> 2) * blockDim.x + threadIdx.x;
  const int stride = (gridDim.x >> 2) * blockDim.x;
  const int Etot = E + n;
  for (int i = tid; i < Etot; i += stride) {
    int s, d;
    if (i < E) { s = esrc[i]; d = edst[i]; } else { s = d = i - E; }
    if (d >= lo && d < hi) {
      int p = atomicAdd(&rowptr[d], 1);
      col[p] = s;
    }
  }
}

// ---------------- features + attention dots (bf16 MFMA) ----------------
template<int HEADS, bool BF16IN>
__global__ void __launch_bounds__(256)
feat_mfma_kernel(const void* __restrict__ In_, const unsigned short* __restrict__ wt,
                 const unsigned short* __restrict__ vt, const float* __restrict__ bias_in,
                 unsigned short* __restrict__ Hout, float* __restrict__ a_src,
                 float* __restrict__ a_dst, int n)
{
  __shared__ unsigned short xs[64][136];
  const int t = threadIdx.x;
  const int w = t >> 6, lane = t & 63;
  const int l15 = lane & 15, lg = lane >> 4;
  const int nbase = blockIdx.x << 6;

  {
    const int r = t >> 2;
    const int c0s = (t & 3) << 5;
    const int node = nbase + r;
    if (BF16IN) {
      const unsigned short* In2 = (const unsigned short*)In_;
      #pragma unroll
      for (int i = 0; i < 4; ++i) {
        unsigned short pk[8];
        if (node < n) {
          short8 v = *(const short8*)&In2[(size_t)node * 128 + c0s + i * 8];
          #pragma unroll
          for (int j = 0; j < 8; ++j) {
            float f = bf2f((unsigned short)v[j]) + bias_in[c0s + i * 8 + j];
            pk[j] = f2bf(lrelu(f, 0.01f));
          }
        } else {
          #pragma unroll
          for (int j = 0; j < 8; ++j) pk[j] = 0;
        }
        *(short8*)&xs[r][c0s + i * 8] = *(short8*)pk;
      }
    } else {
      const float* In1 = (const float*)In_;
      #pragma unroll
      for (int i = 0; i < 8; ++i) {
        unsigned short pk[4];
        if (node < n) {
          float4 v = *(const float4*)&In1[(size_t)node * 128 + c0s + i * 4];
          pk[0] = f2bf(v.x); pk[1] = f2bf(v.y); pk[2] = f2bf(v.z); pk[3] = f2bf(v.w);
        } else { pk[0] = pk[1] = pk[2] = pk[3] = 0; }
        *(uint2*)&xs[r][c0s + i * 4] = *(uint2*)pk;
      }
    }
  }
  __syncthreads();

  short8 afr[4];
  #pragma unroll
  for (int kc = 0; kc < 4; ++kc)
    afr[kc] = *(const short8*)&xs[w * 16 + l15][kc * 32 + lg * 8];

  const unsigned short* bp[9];
  #pragma unroll
  for (int ct = 0; ct < 8; ++ct)
    bp[ct] = wt + (size_t)(ct * 16 + l15) * 128 + lg * 8;
  bp[8] = vt + (size_t)l15 * 128 + lg * 8;

  f32x4 acc[9];
  #pragma unroll
  for (int ct = 0; ct < 9; ++ct) acc[ct] = (f32x4){0.f, 0.f, 0.f, 0.f};

  short8 bcur[9], bnxt[9];
  #pragma unroll
  for (int ct = 0; ct < 9; ++ct) bcur[ct] = *(const short8*)bp[ct];

  #pragma unroll
  for (int kc = 0; kc < 4; ++kc) {
    if (kc < 3) {
      #pragma unroll
      for (int ct = 0; ct < 9; ++ct)
        bnxt[ct] = *(const short8*)(bp[ct] + (kc + 1) * 32);
    }
    #pragma unroll
    for (int ct = 0; ct < 9; ++ct)
      acc[ct] = __builtin_amdgcn_mfma_f32_16x16x32_bf16(afr[kc], bcur[ct], acc[ct], 0, 0, 0);
    if (kc < 3) {
      #pragma unroll
      for (int ct = 0; ct < 9; ++ct) bcur[ct] = bnxt[ct];
    }
  }
  __syncthreads();

  #pragma unroll
  for (int ct = 0; ct < 8; ++ct)
    #pragma unroll
    for (int r = 0; r < 4; ++r)
      xs[w * 16 + lg * 4 + r][ct * 16 + l15] = f2bf(acc[ct][r]);
  __syncthreads();

  {
    const int r = t >> 2;
    const int c0s = (t & 3) << 5;
    const int node = nbase + r;
    if (node < n) {
      #pragma unroll
      for (int i = 0; i < 4; ++i)
        *(short8*)&Hout[(size_t)node * 128 + c0s + i * 8] = *(const short8*)&xs[r][c0s + i * 8];
    }
  }
  #pragma unroll
  for (int r = 0; r < 4; ++r) {
    const int node = nbase + w * 16 + lg * 4 + r;
    if (node < n) {
      const float v = acc[8][r];
      if (HEADS == 8) {
        if (l15 < 8) a_src[node * 8 + l15] = v;
        else         a_dst[node * 8 + (l15 - 8)] = v;
      } else {
        if (l15 == 0) a_src[node] = v;
        else if (l15 == 8) a_dst[node] = v;
      }
    }
  }
}

// ---------------- CSR gather-aggregate (round-9 8-deep pipelined version) ----------------
template<int HEADS>
__global__ void __launch_bounds__(256)
agg_csr_kernel(const int* __restrict__ rowptr_end, const int* __restrict__ col,
               const float* __restrict__ a_src, const float* __restrict__ a_dst,
               const unsigned short* __restrict__ Hf, unsigned int* __restrict__ agg, int n)
{
  const int wave = threadIdx.x >> 6;
  const int lane = threadIdx.x & 63;
  const int d = blockIdx.x * 4 + wave;
  if (d >= n) return;
  const int beg = (d == 0) ? 0 : rowptr_end[d - 1];
  const int end = rowptr_end[d];

  const int ei = lane >> 3;
  const int hh = (HEADS == 8) ? (lane & 7) : 0;
  const int bh = (HEADS == 8) ? (lane >> 3) : 0;
  const float adv = (HEADS == 8) ? a_dst[d * 8 + hh] : a_dst[d];
  const unsigned int* Hu = (const unsigned int*)Hf;

  float accx = 0.f, accy = 0.f, sum = 0.f;
  const int nb8 = (end - beg) >> 3;
  int sv = 0; float a = 0.f;
  if (nb8 > 0) {
    sv = col[beg + ei];
    a = __expf(lrelu(a_src[sv * HEADS + hh] + adv, 0.2f));
    if (HEADS == 8 || (lane & 7) == 0) sum += a;
  }
  for (int b = 0; b < nb8; ++b) {
    int s[8]; float al[8];
    #pragma unroll
    for (int e = 0; e < 8; ++e) {
      s[e]  = __shfl(sv, e * 8);
      al[e] = __shfl(a, e * 8 + bh);
    }
    unsigned int hv[8];
    #pragma unroll
    for (int e = 0; e < 8; ++e) hv[e] = Hu[(size_t)s[e] * 64 + lane];
    if (b + 1 < nb8) {   // prefetch next batch under the H-load latency
      sv = col[beg + ((b + 1) << 3) + ei];
      a = __expf(lrelu(a_src[sv * HEADS + hh] + adv, 0.2f));
      if (HEADS == 8 || (lane & 7) == 0) sum += a;
    }
    #pragma unroll
    for (int e = 0; e < 8; ++e) {
      accx += al[e] * __uint_as_float(hv[e] << 16);
      accy += al[e] * __uint_as_float(hv[e] & 0xffff0000u);
    }
  }
  {
    const int p0 = beg + (nb8 << 3);
    const int cnt = end - p0;
    if (cnt > 0) {
      int svt = 0; float at = 0.f;
      if (ei < cnt) {
        svt = col[p0 + ei];
        at = __expf(lrelu(a_src[svt * HEADS + hh] + adv, 0.2f));
        if (HEADS == 8 || (lane & 7) == 0) sum += at;
      }
      for (int e = 0; e < cnt; ++e) {
        const float al = __shfl(at, e * 8 + bh);
        const int   sx = __shfl(svt, e * 8);
        const unsigned int hv = Hu[(size_t)sx * 64 + lane];
        accx += al * __uint_as_float(hv << 16);
        accy += al * __uint_as_float(hv & 0xffff0000u);
      }
    }
  }
  sum += __shfl_xor(sum, 8);
  sum += __shfl_xor(sum, 16);
  sum += __shfl_xor(sum, 32);
  const float denom = __shfl(sum, bh) + 1e-16f;
  const float inv = 1.f / denom;
  agg[(size_t)d * 64 + lane] = (unsigned int)f2bf(accx * inv) | ((unsigned int)f2bf(accy * inv) << 16);
}

// ---------------- h@g + cosine vs mu (bf16 MFMA, 32-node tiles, gm'-tile epilogue) ----------------
// 9th B-tile = gm' -> num directly from MFMA; ||mu|| pre-folded. Epilogue = ss reduce only.
__global__ void __launch_bounds__(256)
final_kernel(const unsigned short* __restrict__ agg2b, const float* __restrict__ b2,
             const unsigned short* __restrict__ gt, const unsigned short* __restrict__ gmt,
             float* __restrict__ outp, int n)
{
  __shared__ unsigned short os[32][136];
  const int t = threadIdx.x;
  const int w = t >> 6;
  const int lane = t & 63;
  const int l15 = lane & 15;
  const int lg = lane >> 4;
  const int nbase = blockIdx.x << 5;

  {
    const int r = t >> 3;
    const int c = (t & 7) * 16;
    const int node = nbase + r;
    unsigned short pk[16];
    if (node < n) {
      short8 v0 = *(const short8*)&agg2b[(size_t)node * 128 + c];
      short8 v1 = *(const short8*)&agg2b[(size_t)node * 128 + c + 8];
      #pragma unroll
      for (int j = 0; j < 8; ++j) pk[j]     = f2bf(bf2f((unsigned short)v0[j]) + b2[c + j]);
      #pragma unroll
      for (int j = 0; j < 8; ++j) pk[8 + j] = f2bf(bf2f((unsigned short)v1[j]) + b2[c + 8 + j]);
    } else {
      #pragma unroll
      for (int i = 0; i < 16; ++i) pk[i] = 0;
    }
    *(short8*)&os[r][c]     = *(short8*)&pk[0];
    *(short8*)&os[r][c + 8] = *(short8*)&pk[8];
  }
  __syncthreads();

  short8 afr[2][4];
  #pragma unroll
  for (int rt = 0; rt < 2; ++rt)
    #pragma unroll
    for (int kc = 0; kc < 4; ++kc)
      afr[rt][kc] = *(const short8*)&os[rt * 16 + l15][kc * 32 + lg * 8];

  const unsigned short* gw  = gt  + (size_t)(w * 128 + l15) * 128 + lg * 8;
  const unsigned short* gmw = gmt + (size_t)l15 * 128 + lg * 8;

  f32x4 acc[2][8];
  f32x4 accg[2];
  #pragma unroll
  for (int rt = 0; rt < 2; ++rt) {
    #pragma unroll
    for (int ct = 0; ct < 8; ++ct)
      acc[rt][ct] = (f32x4){0.f, 0.f, 0.f, 0.f};
    accg[rt] = (f32x4){0.f, 0.f, 0.f, 0.f};
  }

  short8 bcur[9], bnxt[9];
  #pragma unroll
  for (int ct = 0; ct < 8; ++ct)
    bcur[ct] = *(const short8*)&gw[(size_t)ct * 2048];
  bcur[8] = *(const short8*)gmw;

  #pragma unroll
  for (int kc = 0; kc < 4; ++kc) {
    if (kc < 3) {
      #pragma unroll
      for (int ct = 0; ct < 8; ++ct)
        bnxt[ct] = *(const short8*)&gw[(size_t)ct * 2048 + (kc + 1) * 32];
      bnxt[8] = *(const short8*)(gmw + (kc + 1) * 32);
    }
    #pragma unroll
    for (int ct = 0; ct < 8; ++ct) {
      acc[0][ct] = __builtin_amdgcn_mfma_f32_16x16x32_bf16(afr[0][kc], bcur[ct], acc[0][ct], 0, 0, 0);
      acc[1][ct] = __builtin_amdgcn_mfma_f32_16x16x32_bf16(afr[1][kc], bcur[ct], acc[1][ct], 0, 0, 0);
    }
    accg[0] = __builtin_amdgcn_mfma_f32_16x16x32_bf16(afr[0][kc], bcur[8], accg[0], 0, 0, 0);
    accg[1] = __builtin_amdgcn_mfma_f32_16x16x32_bf16(afr[1][kc], bcur[8], accg[1], 0, 0, 0);
    if (kc < 3) {
      #pragma unroll
      for (int ct = 0; ct < 9; ++ct) bcur[ct] = bnxt[ct];
    }
  }

  const int k0 = w * 2, k1 = w * 2 + 1;
  #pragma unroll
  for (int rt = 0; rt < 2; ++rt) {
    float ss0[4] = {0.f, 0.f, 0.f, 0.f};
    float ss1[4] = {0.f, 0.f, 0.f, 0.f};
    #pragma unroll
    for (int ct = 0; ct < 4; ++ct) {
      const f32x4 a = acc[rt][ct];
      const f32x4 b = acc[rt][4 + ct];
      #pragma unroll
      for (int r = 0; r < 4; ++r) {
        ss0[r] += a[r] * a[r];
        ss1[r] += b[r] * b[r];
      }
    }
    #pragma unroll
    for (int r = 0; r < 4; ++r) {
      ss0[r] += __shfl_xor(ss0[r], 1); ss1[r] += __shfl_xor(ss1[r], 1);
      ss0[r] += __shfl_xor(ss0[r], 2); ss1[r] += __shfl_xor(ss1[r], 2);
      ss0[r] += __shfl_xor(ss0[r], 4); ss1[r] += __shfl_xor(ss1[r], 4);
      ss0[r] += __shfl_xor(ss0[r], 8); ss1[r] += __shfl_xor(ss1[r], 8);
    }
    #pragma unroll
    for (int r = 0; r < 4; ++r) {
      const int node = nbase + rt * 16 + lg * 4 + r;
      if (node < n) {
        const float nv = accg[rt][r];
        if (l15 == k0)      outp[(size_t)node * 8 + k0] = nv / fmaxf(sqrtf(ss0[r]), 1e-8f);
        else if (l15 == k1) outp[(size_t)node * 8 + k1] = nv / fmaxf(sqrtf(ss1[r]), 1e-8f);
      }
    }
  }
}

extern "C" void kernel_launch(void* const* d_in, const int* in_sizes, int n_in,
                              void* d_out, int out_size, void* d_ws, size_t ws_size,
                              hipStream_t stream)
{
  const float* x   = (const float*)d_in[0];
  const int*   eix = (const int*)d_in[1];
  const float* W1  = (const float*)d_in[2];
  const float* as1 = (const float*)d_in[3];
  const float* ad1 = (const float*)d_in[4];
  const float* b1  = (const float*)d_in[5];
  const float* W2  = (const float*)d_in[6];
  const float* as2 = (const float*)d_in[7];
  const float* ad2 = (const float*)d_in[8];
  const float* b2  = (const float*)d_in[9];
  const float* g   = (const float*)d_in[10];
  const float* mu  = (const float*)d_in[11];
  float* outp = (float*)d_out;

  const int n    = in_sizes[0] / 128;
  const int E    = in_sizes[1] / 2;
  const int* esrc = eix;
  const int* edst = eix + E;

  unsigned short* hb  = (unsigned short*)d_ws;
  unsigned short* gt  = hb + (size_t)n * 128;
  unsigned short* wt1 = gt + 512 * 128;
  unsigned short* vt1 = wt1 + 128 * 128;
  unsigned short* wt2 = vt1 + 16 * 128;
  unsigned short* vt2 = wt2 + 128 * 128;
  unsigned short* gmt = vt2 + 16 * 128;
  unsigned short* agg_b = (unsigned short*)((char*)d_ws + (size_t)n * 512);
  float* asrc   = (float*)((char*)d_ws + (size_t)n * 1024);
  float* adst   = asrc + (size_t)n * 8;
  int*   rowptr = (int*)(adst + (size_t)n * 8);
  int*   col    = rowptr + n;
  int*   deg    = (int*)agg_b;
  int*   blksum = deg + n;

  // ---------------- param prep (fused) ----------------
  prep_kernel<<<161, 256, 0, stream>>>(g, gt, W1, as1, ad1, wt1, vt1,
                                       W2, as2, ad2, wt2, vt2, mu, gmt);

  // ---------------- CSR build (by destination, self-loops included) ----------------
  const int nb = (n + 2047) / 2048;
  hipMemsetAsync(deg, 0, (size_t)n * sizeof(int), stream);
  deg_count_kernel<<<2048, 256, 0, stream>>>(edst, deg, E, n);
  scan1_kernel<<<nb, 256, 0, stream>>>(deg, rowptr, blksum, n);
  scan2_kernel<<<1, 64, 0, stream>>>(blksum, nb);
  scan3_kernel<<<(n + 255) / 256, 256, 0, stream>>>(rowptr, blksum, n);
  scatter_kernel<<<2048, 256, 0, stream>>>(esrc, edst, rowptr, col, E, n);

  // ---------------- conv1 (heads=8, C=16) ----------------
  feat_mfma_kernel<8, false><<<(n + 63) / 64, 256, 0, stream>>>(
      x, wt1, vt1, nullptr, hb, asrc, adst, n);
  agg_csr_kernel<8><<<(n + 3) / 4, 256, 0, stream>>>(
      rowptr, col, asrc, adst, hb, (unsigned int*)agg_b, n);

  // ---------------- conv2 (heads=1, C=128) ----------------
  feat_mfma_kernel<1, true><<<(n + 63) / 64, 256, 0, stream>>>(
      agg_b, wt2, vt2, b1, hb, asrc, adst, n);
  agg_csr_kernel<1><<<(n + 3) / 4, 256, 0, stream>>>(
      rowptr, col, asrc, adst, hb, (unsigned int*)agg_b, n);

  // ---------------- h@g + cosine vs mu ----------------
  final_kernel<<<(n + 31) / 32, 256, 0, stream>>>(agg_b, b2, gt, gmt, outp, n);
}

// Round 13
// 478.657 us; speedup vs baseline: 1.0443x; 1.0299x over previous
//
#include <hip/hip_runtime.h>
#include <hip/hip_bf16.h>

typedef short short8 __attribute__((ext_vector_type(8)));
typedef float f32x4 __attribute__((ext_vector_type(4)));

__device__ __forceinline__ float lrelu(float x, float s) { return x > 0.f ? x : x * s; }

__device__ __forceinline__ unsigned short f2bf(float x) {
  union { __hip_bfloat16 b; unsigned short u; } cv;
  cv.b = __float2bfloat16(x);
  return cv.u;
}
__device__ __forceinline__ float bf2f(unsigned short u) {
  return __uint_as_float(((unsigned int)u) << 16);
}

// ---------------- unified param prep ----------------
// blocks 0..31: g -> gt ; 32..95: W1 ; 96..159: W2 ; 160: gm' = (g contracted with mu)/||mu_k||
__global__ void __launch_bounds__(256)
prep_kernel(const float* __restrict__ g, unsigned short* __restrict__ gt,
            const float* __restrict__ W1, const float* __restrict__ as1,
            const float* __restrict__ ad1, unsigned short* __restrict__ wt1,
            unsigned short* __restrict__ vt1,
            const float* __restrict__ W2, const float* __restrict__ as2,
            const float* __restrict__ ad2, unsigned short* __restrict__ wt2,
            unsigned short* __restrict__ vt2,
            const float* __restrict__ mu, unsigned short* __restrict__ gmt)
{
  __shared__ float ts[32][68];
  __shared__ float ss[2][128], sd[2][128];
  __shared__ float msq[8];
  const int b = blockIdx.x;
  const int t = threadIdx.x;
  if (b < 32) {
    const int kb = (b >> 3) * 32;
    const int cb = (b & 7) * 64;
    {
      const int r = t >> 3;
      const int c = (t & 7) * 8;
      float4 v0 = *(const float4*)&g[(size_t)(kb + r) * 512 + cb + c];
      float4 v1 = *(const float4*)&g[(size_t)(kb + r) * 512 + cb + c + 4];
      *(float4*)&ts[r][c] = v0;
      *(float4*)&ts[r][c + 4] = v1;
    }
    __syncthreads();
    {
      const int c = t >> 2;
      const int k0 = (t & 3) * 8;
      unsigned short pk[8];
      #pragma unroll
      for (int j = 0; j < 8; ++j) pk[j] = f2bf(ts[k0 + j][c]);
      *(short8*)&gt[(size_t)(cb + c) * 128 + kb + k0] = *(short8*)pk;
    }
  } else if (b < 160) {
    const int isW2 = (b >= 96) ? 1 : 0;
    const float* W  = isW2 ? W2 : W1;
    const float* as = isW2 ? as2 : as1;
    const float* ad = isW2 ? ad2 : ad1;
    unsigned short* wt = isW2 ? wt2 : wt1;
    unsigned short* vt = isW2 ? vt2 : vt1;
    const int HEADS = isW2 ? 1 : 8;
    const int kk = t >> 7;
    const int c  = t & 127;
    const int k  = ((b - (isW2 ? 96 : 32)) << 1) + kk;
    const float wv = W[k * 128 + c];
    wt[c * 128 + k] = f2bf(wv);
    ss[kk][c] = wv * as[c];
    sd[kk][c] = wv * ad[c];
    __syncthreads();
    if (c < 16) {
      const int C = 128 / HEADS;
      const int h = (c < 8) ? c : c - 8;
      float s = 0.f;
      if (h < HEADS) {
        const float* sb = (c < 8) ? ss[kk] : sd[kk];
        for (int j = 0; j < C; ++j) s += sb[h * C + j];
      }
      vt[c * 128 + k] = f2bf(s);
    }
  } else {
    if (t < 8) {
      float s = 0.f;
      for (int m = 0; m < 64; ++m) { const float v = mu[t * 64 + m]; s += v * v; }
      msq[t] = fmaxf(sqrtf(s), 1e-8f);
    }
    __syncthreads();
    #pragma unroll
    for (int p = 0; p < 4; ++p) {
      const int idx = t + p * 256;
      const int j = idx >> 3, k = idx & 7;
      float s = 0.f;
      for (int m = 0; m < 64; ++m) s += mu[k * 64 + m] * g[(size_t)j * 512 + k * 64 + m];
      gmt[k * 128 + j] = f2bf(s / msq[k]);
      gmt[(8 + (idx >> 7)) * 128 + (idx & 127)] = 0;
    }
  }
}

// ---------------- CSR build ----------------
__global__ void __launch_bounds__(256)
deg_count_kernel(const int* __restrict__ edst, int* __restrict__ deg, int E, int n) {
  const int grp = blockIdx.x & 3;
  const int lo = (int)(((long long)n * grp) >> 2);
  const int hi = (int)(((long long)n * (grp + 1)) >> 2);
  const int tid = (blockIdx.x >> 2) * blockDim.x + threadIdx.x;
  const int stride = (gridDim.x >> 2) * blockDim.x;
  for (int i = tid; i < E; i += stride) {
    const int d = edst[i];
    if (d >= lo && d < hi) atomicAdd(&deg[d], 1);
  }
}

__global__ void __launch_bounds__(256)
scan1_kernel(const int* __restrict__ deg, int* __restrict__ out,
             int* __restrict__ blksum, int n) {
  __shared__ int ts[256];
  const int t = threadIdx.x;
  const int base = blockIdx.x * 2048 + t * 8;
  int v[8]; int s = 0;
  #pragma unroll
  for (int i = 0; i < 8; ++i) {
    int x = (base + i < n) ? deg[base + i] + 1 : 0;   // +1 = self-loop
    v[i] = s; s += x;
  }
  ts[t] = s;
  __syncthreads();
  for (int off = 1; off < 256; off <<= 1) {
    int add = (t >= off) ? ts[t - off] : 0;
    __syncthreads();
    ts[t] += add;
    __syncthreads();
  }
  const int excl = ts[t] - s;
  #pragma unroll
  for (int i = 0; i < 8; ++i)
    if (base + i < n) out[base + i] = excl + v[i];
  if (t == 255) blksum[blockIdx.x] = ts[255];
}

__global__ void scan2_kernel(int* __restrict__ blksum, int nb) {
  const int t = threadIdx.x;
  int v = (t < nb) ? blksum[t] : 0;
  #pragma unroll
  for (int off = 1; off < 64; off <<= 1) {
    int u = __shfl_up(v, off);
    if (t >= off) v += u;
  }
  if (t < nb) blksum[t] = v;
}

__global__ void scan3_kernel(int* __restrict__ out, const int* __restrict__ blksum, int n) {
  int i = blockIdx.x * blockDim.x + threadIdx.x;
  if (i >= n) return;
  int b = i >> 11;
  if (b > 0) out[i] += blksum[b - 1];
}

__global__ void __launch_bounds__(256)
scatter_kernel(const int* __restrict__ esrc, const int* __restrict__ edst,
               int* __restrict__ rowptr, int* __restrict__ col,
               int E, int n) {
  const int grp = blockIdx.x & 3;
  const int lo = (int)(((long long)n * grp) >> 2);
  const int hi = (int)(((long long)n * (grp + 1)) >> 2);
  const int tid = (blockIdx.x >> 2) * blockDim.x + threadIdx.x;
  const int stride = (gridDim.x >> 2) * blockDim.x;
  const int Etot = E + n;
  for (int i = tid; i < Etot; i += stride) {
    int s, d;
    if (i < E) { s = esrc[i]; d = edst[i]; } else { s = d = i - E; }
    if (d >= lo && d < hi) {
      int p = atomicAdd(&rowptr[d], 1);
      col[p] = s;
    }
  }
}

// ---------------- features + attention dots (bf16 MFMA) ----------------
// I8OUT: H stored as int8 with per-row scale (hscale[n]); else bf16.
template<int HEADS, bool BF16IN, bool I8OUT>
__global__ void __launch_bounds__(256)
feat_mfma_kernel(const void* __restrict__ In_, const unsigned short* __restrict__ wt,
                 const unsigned short* __restrict__ vt, const float* __restrict__ bias_in,
                 void* __restrict__ Hout_, float* __restrict__ hscale,
                 float* __restrict__ a_src, float* __restrict__ a_dst, int n)
{
  __shared__ unsigned short xs[64][136];
  const int t = threadIdx.x;
  const int w = t >> 6, lane = t & 63;
  const int l15 = lane & 15, lg = lane >> 4;
  const int nbase = blockIdx.x << 6;

  {
    const int r = t >> 2;
    const int c0s = (t & 3) << 5;
    const int node = nbase + r;
    if (BF16IN) {
      const unsigned short* In2 = (const unsigned short*)In_;
      #pragma unroll
      for (int i = 0; i < 4; ++i) {
        unsigned short pk[8];
        if (node < n) {
          short8 v = *(const short8*)&In2[(size_t)node * 128 + c0s + i * 8];
          #pragma unroll
          for (int j = 0; j < 8; ++j) {
            float f = bf2f((unsigned short)v[j]) + bias_in[c0s + i * 8 + j];
            pk[j] = f2bf(lrelu(f, 0.01f));
          }
        } else {
          #pragma unroll
          for (int j = 0; j < 8; ++j) pk[j] = 0;
        }
        *(short8*)&xs[r][c0s + i * 8] = *(short8*)pk;
      }
    } else {
      const float* In1 = (const float*)In_;
      #pragma unroll
      for (int i = 0; i < 8; ++i) {
        unsigned short pk[4];
        if (node < n) {
          float4 v = *(const float4*)&In1[(size_t)node * 128 + c0s + i * 4];
          pk[0] = f2bf(v.x); pk[1] = f2bf(v.y); pk[2] = f2bf(v.z); pk[3] = f2bf(v.w);
        } else { pk[0] = pk[1] = pk[2] = pk[3] = 0; }
        *(uint2*)&xs[r][c0s + i * 4] = *(uint2*)pk;
      }
    }
  }
  __syncthreads();

  short8 afr[4];
  #pragma unroll
  for (int kc = 0; kc < 4; ++kc)
    afr[kc] = *(const short8*)&xs[w * 16 + l15][kc * 32 + lg * 8];

  const unsigned short* bp[9];
  #pragma unroll
  for (int ct = 0; ct < 8; ++ct)
    bp[ct] = wt + (size_t)(ct * 16 + l15) * 128 + lg * 8;
  bp[8] = vt + (size_t)l15 * 128 + lg * 8;

  f32x4 acc[9];
  #pragma unroll
  for (int ct = 0; ct < 9; ++ct) acc[ct] = (f32x4){0.f, 0.f, 0.f, 0.f};

  short8 bcur[9], bnxt[9];
  #pragma unroll
  for (int ct = 0; ct < 9; ++ct) bcur[ct] = *(const short8*)bp[ct];

  #pragma unroll
  for (int kc = 0; kc < 4; ++kc) {
    if (kc < 3) {
      #pragma unroll
      for (int ct = 0; ct < 9; ++ct)
        bnxt[ct] = *(const short8*)(bp[ct] + (kc + 1) * 32);
    }
    #pragma unroll
    for (int ct = 0; ct < 9; ++ct)
      acc[ct] = __builtin_amdgcn_mfma_f32_16x16x32_bf16(afr[kc], bcur[ct], acc[ct], 0, 0, 0);
    if (kc < 3) {
      #pragma unroll
      for (int ct = 0; ct < 9; ++ct) bcur[ct] = bnxt[ct];
    }
  }
  __syncthreads();   // afr reads done before xs reuse

  if (I8OUT) {
    unsigned char* xb = (unsigned char*)xs;      // row stride 272 B (16B-aligned)
    float inv127[4], scl[4];
    #pragma unroll
    for (int r = 0; r < 4; ++r) {
      float m = 0.f;
      #pragma unroll
      for (int ct = 0; ct < 8; ++ct) m = fmaxf(m, fabsf(acc[ct][r]));
      m = fmaxf(m, __shfl_xor(m, 1));
      m = fmaxf(m, __shfl_xor(m, 2));
      m = fmaxf(m, __shfl_xor(m, 4));
      m = fmaxf(m, __shfl_xor(m, 8));
      m = fmaxf(m, 1e-12f);
      inv127[r] = 127.f / m;
      scl[r] = m * (1.f / 127.f);
    }
    #pragma unroll
    for (int ct = 0; ct < 8; ++ct)
      #pragma unroll
      for (int r = 0; r < 4; ++r) {
        const int q = __float2int_rn(acc[ct][r] * inv127[r]);
        xb[(w * 16 + lg * 4 + r) * 272 + ct * 16 + l15] = (unsigned char)q;
      }
    if (l15 == 0) {
      #pragma unroll
      for (int r = 0; r < 4; ++r) {
        const int node = nbase + w * 16 + lg * 4 + r;
        if (node < n) hscale[node] = scl[r];
      }
    }
    __syncthreads();
    {
      const int rr = t >> 2;
      const int cc = (t & 3) * 32;
      const int node = nbase + rr;
      if (node < n) {
        unsigned char* H8 = (unsigned char*)Hout_;
        *(uint4*)&H8[(size_t)node * 128 + cc]      = *(const uint4*)&xb[rr * 272 + cc];
        *(uint4*)&H8[(size_t)node * 128 + cc + 16] = *(const uint4*)&xb[rr * 272 + cc + 16];
      }
    }
  } else {
    #pragma unroll
    for (int ct = 0; ct < 8; ++ct)
      #pragma unroll
      for (int r = 0; r < 4; ++r)
        xs[w * 16 + lg * 4 + r][ct * 16 + l15] = f2bf(acc[ct][r]);
    __syncthreads();
    {
      const int r = t >> 2;
      const int c0s = (t & 3) << 5;
      const int node = nbase + r;
      if (node < n) {
        unsigned short* Hb = (unsigned short*)Hout_;
        #pragma unroll
        for (int i = 0; i < 4; ++i)
          *(short8*)&Hb[(size_t)node * 128 + c0s + i * 8] = *(const short8*)&xs[r][c0s + i * 8];
      }
    }
  }

  #pragma unroll
  for (int r = 0; r < 4; ++r) {
    const int node = nbase + w * 16 + lg * 4 + r;
    if (node < n) {
      const float v = acc[8][r];
      if (HEADS == 8) {
        if (l15 < 8) a_src[node * 8 + l15] = v;
        else         a_dst[node * 8 + (l15 - 8)] = v;
      } else {
        if (l15 == 0) a_src[node] = v;
        else if (l15 == 8) a_dst[node] = v;
      }
    }
  }
}

// ---------------- CSR gather-aggregate (8-deep pipelined; H int8+scale or bf16) ----------------
template<int HEADS, bool I8H>
__global__ void __launch_bounds__(256)
agg_csr_kernel(const int* __restrict__ rowptr_end, const int* __restrict__ col,
               const float* __restrict__ a_src, const float* __restrict__ a_dst,
               const void* __restrict__ Hf_, const float* __restrict__ hscale,
               unsigned int* __restrict__ agg, int n)
{
  const int wave = threadIdx.x >> 6;
  const int lane = threadIdx.x & 63;
  const int d = blockIdx.x * 4 + wave;
  if (d >= n) return;
  const int beg = (d == 0) ? 0 : rowptr_end[d - 1];
  const int end = rowptr_end[d];

  const int ei = lane >> 3;
  const int hh = (HEADS == 8) ? (lane & 7) : 0;
  const int bh = (HEADS == 8) ? (lane >> 3) : 0;
  const float adv = (HEADS == 8) ? a_dst[d * 8 + hh] : a_dst[d];
  const unsigned int* Hu = (const unsigned int*)Hf_;
  const unsigned short* H16 = (const unsigned short*)Hf_;

  float accx = 0.f, accy = 0.f, sum = 0.f;
  const int nb8 = (end - beg) >> 3;
  int sv = 0; float a = 0.f, Sv = 0.f;
  if (nb8 > 0) {
    sv = col[beg + ei];
    a = __expf(lrelu(a_src[sv * HEADS + hh] + adv, 0.2f));
    if (I8H) Sv = hscale[sv];
    if (HEADS == 8 || (lane & 7) == 0) sum += a;
  }
  for (int b = 0; b < nb8; ++b) {
    int s[8]; float al[8];
    #pragma unroll
    for (int e = 0; e < 8; ++e) {
      s[e]  = __shfl(sv, e * 8);
      al[e] = __shfl(a, e * 8 + bh);
      if (I8H) al[e] *= __shfl(Sv, e * 8);
    }
    unsigned int hv[8];
    if (I8H) {
      #pragma unroll
      for (int e = 0; e < 8; ++e) hv[e] = H16[(size_t)s[e] * 64 + lane];
    } else {
      #pragma unroll
      for (int e = 0; e < 8; ++e) hv[e] = Hu[(size_t)s[e] * 64 + lane];
    }
    if (b + 1 < nb8) {   // prefetch next batch under the gather latency
      sv = col[beg + ((b + 1) << 3) + ei];
      a = __expf(lrelu(a_src[sv * HEADS + hh] + adv, 0.2f));
      if (I8H) Sv = hscale[sv];
      if (HEADS == 8 || (lane & 7) == 0) sum += a;
    }
    #pragma unroll
    for (int e = 0; e < 8; ++e) {
      if (I8H) {
        const int wv = (int)hv[e];
        accx += al[e] * (float)((wv << 24) >> 24);
        accy += al[e] * (float)((wv << 16) >> 24);
      } else {
        accx += al[e] * __uint_as_float(hv[e] << 16);
        accy += al[e] * __uint_as_float(hv[e] & 0xffff0000u);
      }
    }
  }
  {
    const int p0 = beg + (nb8 << 3);
    const int cnt = end - p0;
    if (cnt > 0) {
      int svt = 0; float at = 0.f, Svt = 0.f;
      if (ei < cnt) {
        svt = col[p0 + ei];
        at = __expf(lrelu(a_src[svt * HEADS + hh] + adv, 0.2f));
        if (I8H) Svt = hscale[svt];
        if (HEADS == 8 || (lane & 7) == 0) sum += at;
      }
      for (int e = 0; e < cnt; ++e) {
        float al = __shfl(at, e * 8 + bh);
        if (I8H) al *= __shfl(Svt, e * 8);
        const int sx = __shfl(svt, e * 8);
        if (I8H) {
          const int wv = (int)H16[(size_t)sx * 64 + lane];
          accx += al * (float)((wv << 24) >> 24);
          accy += al * (float)((wv << 16) >> 24);
        } else {
          const unsigned int hv = Hu[(size_t)sx * 64 + lane];
          accx += al * __uint_as_float(hv << 16);
          accy += al * __uint_as_float(hv & 0xffff0000u);
        }
      }
    }
  }
  sum += __shfl_xor(sum, 8);
  sum += __shfl_xor(sum, 16);
  sum += __shfl_xor(sum, 32);
  const float denom = __shfl(sum, bh) + 1e-16f;
  const float inv = 1.f / denom;
  agg[(size_t)d * 64 + lane] = (unsigned int)f2bf(accx * inv) | ((unsigned int)f2bf(accy * inv) << 16);
}

// ---------------- h@g + cosine vs mu (bf16 MFMA, 32-node tiles, gm'-tile epilogue) ----------------
__global__ void __launch_bounds__(256)
final_kernel(const unsigned short* __restrict__ agg2b, const float* __restrict__ b2,
             const unsigned short* __restrict__ gt, const unsigned short* __restrict__ gmt,
             float* __restrict__ outp, int n)
{
  __shared__ unsigned short os[32][136];
  const int t = threadIdx.x;
  const int w = t >> 6;
  const int lane = t & 63;
  const int l15 = lane & 15;
  const int lg = lane >> 4;
  const int nbase = blockIdx.x << 5;

  {
    const int r = t >> 3;
    const int c = (t & 7) * 16;
    const int node = nbase + r;
    unsigned short pk[16];
    if (node < n) {
      short8 v0 = *(const short8*)&agg2b[(size_t)node * 128 + c];
      short8 v1 = *(const short8*)&agg2b[(size_t)node * 128 + c + 8];
      #pragma unroll
      for (int j = 0; j < 8; ++j) pk[j]     = f2bf(bf2f((unsigned short)v0[j]) + b2[c + j]);
      #pragma unroll
      for (int j = 0; j < 8; ++j) pk[8 + j] = f2bf(bf2f((unsigned short)v1[j]) + b2[c + 8 + j]);
    } else {
      #pragma unroll
      for (int i = 0; i < 16; ++i) pk[i] = 0;
    }
    *(short8*)&os[r][c]     = *(short8*)&pk[0];
    *(short8*)&os[r][c + 8] = *(short8*)&pk[8];
  }
  __syncthreads();

  short8 afr[2][4];
  #pragma unroll
  for (int rt = 0; rt < 2; ++rt)
    #pragma unroll
    for (int kc = 0; kc < 4; ++kc)
      afr[rt][kc] = *(const short8*)&os[rt * 16 + l15][kc * 32 + lg * 8];

  const unsigned short* gw  = gt  + (size_t)(w * 128 + l15) * 128 + lg * 8;
  const unsigned short* gmw = gmt + (size_t)l15 * 128 + lg * 8;

  f32x4 acc[2][8];
  f32x4 accg[2];
  #pragma unroll
  for (int rt = 0; rt < 2; ++rt) {
    #pragma unroll
    for (int ct = 0; ct < 8; ++ct)
      acc[rt][ct] = (f32x4){0.f, 0.f, 0.f, 0.f};
    accg[rt] = (f32x4){0.f, 0.f, 0.f, 0.f};
  }

  short8 bcur[9], bnxt[9];
  #pragma unroll
  for (int ct = 0; ct < 8; ++ct)
    bcur[ct] = *(const short8*)&gw[(size_t)ct * 2048];
  bcur[8] = *(const short8*)gmw;

  #pragma unroll
  for (int kc = 0; kc < 4; ++kc) {
    if (kc < 3) {
      #pragma unroll
      for (int ct = 0; ct < 8; ++ct)
        bnxt[ct] = *(const short8*)&gw[(size_t)ct * 2048 + (kc + 1) * 32];
      bnxt[8] = *(const short8*)(gmw + (kc + 1) * 32);
    }
    #pragma unroll
    for (int ct = 0; ct < 8; ++ct) {
      acc[0][ct] = __builtin_amdgcn_mfma_f32_16x16x32_bf16(afr[0][kc], bcur[ct], acc[0][ct], 0, 0, 0);
      acc[1][ct] = __builtin_amdgcn_mfma_f32_16x16x32_bf16(afr[1][kc], bcur[ct], acc[1][ct], 0, 0, 0);
    }
    accg[0] = __builtin_amdgcn_mfma_f32_16x16x32_bf16(afr[0][kc], bcur[8], accg[0], 0, 0, 0);
    accg[1] = __builtin_amdgcn_mfma_f32_16x16x32_bf16(afr[1][kc], bcur[8], accg[1], 0, 0, 0);
    if (kc < 3) {
      #pragma unroll
      for (int ct = 0; ct < 9; ++ct) bcur[ct] = bnxt[ct];
    }
  }

  const int k0 = w * 2, k1 = w * 2 + 1;
  #pragma unroll
  for (int rt = 0; rt < 2; ++rt) {
    float ss0[4] = {0.f, 0.f, 0.f, 0.f};
    float ss1[4] = {0.f, 0.f, 0.f, 0.f};
    #pragma unroll
    for (int ct = 0; ct < 4; ++ct) {
      const f32x4 a = acc[rt][ct];
      const f32x4 b = acc[rt][4 + ct];
      #pragma unroll
      for (int r = 0; r < 4; ++r) {
        ss0[r] += a[r] * a[r];
        ss1[r] += b[r] * b[r];
      }
    }
    #pragma unroll
    for (int r = 0; r < 4; ++r) {
      ss0[r] += __shfl_xor(ss0[r], 1); ss1[r] += __shfl_xor(ss1[r], 1);
      ss0[r] += __shfl_xor(ss0[r], 2); ss1[r] += __shfl_xor(ss1[r], 2);
      ss0[r] += __shfl_xor(ss0[r], 4); ss1[r] += __shfl_xor(ss1[r], 4);
      ss0[r] += __shfl_xor(ss0[r], 8); ss1[r] += __shfl_xor(ss1[r], 8);
    }
    #pragma unroll
    for (int r = 0; r < 4; ++r) {
      const int node = nbase + rt * 16 + lg * 4 + r;
      if (node < n) {
        const float nv = accg[rt][r];
        if (l15 == k0)      outp[(size_t)node * 8 + k0] = nv / fmaxf(sqrtf(ss0[r]), 1e-8f);
        else if (l15 == k1) outp[(size_t)node * 8 + k1] = nv / fmaxf(sqrtf(ss1[r]), 1e-8f);
      }
    }
  }
}

extern "C" void kernel_launch(void* const* d_in, const int* in_sizes, int n_in,
                              void* d_out, int out_size, void* d_ws, size_t ws_size,
                              hipStream_t stream)
{
  const float* x   = (const float*)d_in[0];
  const int*   eix = (const int*)d_in[1];
  const float* W1  = (const float*)d_in[2];
  const float* as1 = (const float*)d_in[3];
  const float* ad1 = (const float*)d_in[4];
  const float* b1  = (const float*)d_in[5];
  const float* W2  = (const float*)d_in[6];
  const float* as2 = (const float*)d_in[7];
  const float* ad2 = (const float*)d_in[8];
  const float* b2  = (const float*)d_in[9];
  const float* g   = (const float*)d_in[10];
  const float* mu  = (const float*)d_in[11];
  float* outp = (float*)d_out;

  const int n    = in_sizes[0] / 128;
  const int E    = in_sizes[1] / 2;
  const int* esrc = eix;
  const int* edst = eix + E;

  unsigned short* hb  = (unsigned short*)d_ws;   // H1 int8 (128B/row) or H2 bf16 (256B/row)
  unsigned short* gt  = hb + (size_t)n * 128;
  unsigned short* wt1 = gt + 512 * 128;
  unsigned short* vt1 = wt1 + 128 * 128;
  unsigned short* wt2 = vt1 + 16 * 128;
  unsigned short* vt2 = wt2 + 128 * 128;
  unsigned short* gmt = vt2 + 16 * 128;
  unsigned short* agg_b = (unsigned short*)((char*)d_ws + (size_t)n * 512);
  float* asrc   = (float*)((char*)d_ws + (size_t)n * 1024);
  float* adst   = asrc + (size_t)n * 8;
  int*   rowptr = (int*)(adst + (size_t)n * 8);
  int*   col    = rowptr + n;
  float* hscale = (float*)(col + (size_t)E + n);
  int*   deg    = (int*)agg_b;
  int*   blksum = deg + n;

  // ---------------- param prep (fused) ----------------
  prep_kernel<<<161, 256, 0, stream>>>(g, gt, W1, as1, ad1, wt1, vt1,
                                       W2, as2, ad2, wt2, vt2, mu, gmt);

  // ---------------- CSR build (by destination, self-loops included) ----------------
  const int nb = (n + 2047) / 2048;
  hipMemsetAsync(deg, 0, (size_t)n * sizeof(int), stream);
  deg_count_kernel<<<2048, 256, 0, stream>>>(edst, deg, E, n);
  scan1_kernel<<<nb, 256, 0, stream>>>(deg, rowptr, blksum, n);
  scan2_kernel<<<1, 64, 0, stream>>>(blksum, nb);
  scan3_kernel<<<(n + 255) / 256, 256, 0, stream>>>(rowptr, blksum, n);
  scatter_kernel<<<2048, 256, 0, stream>>>(esrc, edst, rowptr, col, E, n);

  // ---------------- conv1 (heads=8, C=16): H in int8 + per-row scale ----------------
  feat_mfma_kernel<8, false, true><<<(n + 63) / 64, 256, 0, stream>>>(
      x, wt1, vt1, nullptr, hb, hscale, asrc, adst, n);
  agg_csr_kernel<8, true><<<(n + 3) / 4, 256, 0, stream>>>(
      rowptr, col, asrc, adst, hb, hscale, (unsigned int*)agg_b, n);

  // ---------------- conv2 (heads=1, C=128): H in bf16 ----------------
  feat_mfma_kernel<1, true, false><<<(n + 63) / 64, 256, 0, stream>>>(
      agg_b, wt2, vt2, b1, hb, nullptr, asrc, adst, n);
  agg_csr_kernel<1, false><<<(n + 3) / 4, 256, 0, stream>>>(
      rowptr, col, asrc, adst, hb, nullptr, (unsigned int*)agg_b, n);

  // ---------------- h@g + cosine vs mu ----------------
  final_kernel<<<(n + 31) / 32, 256, 0, stream>>>(agg_b, b2, gt, gmt, outp, n);
}

// Round 14
// 467.480 us; speedup vs baseline: 1.0692x; 1.0239x over previous
//
#include <hip/hip_runtime.h>
#include <hip/hip_bf16.h>

typedef short short8 __attribute__((ext_vector_type(8)));
typedef float f32x4 __attribute__((ext_vector_type(4)));

__device__ __forceinline__ float lrelu(float x, float s) { return x > 0.f ? x : x * s; }

__device__ __forceinline__ unsigned short f2bf(float x) {
  union { __hip_bfloat16 b; unsigned short u; } cv;
  cv.b = __float2bfloat16(x);
  return cv.u;
}
__device__ __forceinline__ float bf2f(unsigned short u) {
  return __uint_as_float(((unsigned int)u) << 16);
}

#define NSCAT 2048

// ---------------- unified param prep + deg_count ----------------
// blocks 0..31: g -> gt ; 32..95: W1 ; 96..159: W2 ; 160: gm' ; 161..: deg_count
__global__ void __launch_bounds__(256)
prep_kernel(const float* __restrict__ g, unsigned short* __restrict__ gt,
            const float* __restrict__ W1, const float* __restrict__ as1,
            const float* __restrict__ ad1, unsigned short* __restrict__ wt1,
            unsigned short* __restrict__ vt1,
            const float* __restrict__ W2, const float* __restrict__ as2,
            const float* __restrict__ ad2, unsigned short* __restrict__ wt2,
            unsigned short* __restrict__ vt2,
            const float* __restrict__ mu, unsigned short* __restrict__ gmt,
            const int* __restrict__ edst, int* __restrict__ deg, int E, int n)
{
  __shared__ float ts[32][68];
  __shared__ float ss[2][128], sd[2][128];
  __shared__ float msq[8];
  const int b = blockIdx.x;
  const int t = threadIdx.x;
  if (b < 32) {
    const int kb = (b >> 3) * 32;
    const int cb = (b & 7) * 64;
    {
      const int r = t >> 3;
      const int c = (t & 7) * 8;
      float4 v0 = *(const float4*)&g[(size_t)(kb + r) * 512 + cb + c];
      float4 v1 = *(const float4*)&g[(size_t)(kb + r) * 512 + cb + c + 4];
      *(float4*)&ts[r][c] = v0;
      *(float4*)&ts[r][c + 4] = v1;
    }
    __syncthreads();
    {
      const int c = t >> 2;
      const int k0 = (t & 3) * 8;
      unsigned short pk[8];
      #pragma unroll
      for (int j = 0; j < 8; ++j) pk[j] = f2bf(ts[k0 + j][c]);
      *(short8*)&gt[(size_t)(cb + c) * 128 + kb + k0] = *(short8*)pk;
    }
  } else if (b < 160) {
    const int isW2 = (b >= 96) ? 1 : 0;
    const float* W  = isW2 ? W2 : W1;
    const float* as = isW2 ? as2 : as1;
    const float* ad = isW2 ? ad2 : ad1;
    unsigned short* wt = isW2 ? wt2 : wt1;
    unsigned short* vt = isW2 ? vt2 : vt1;
    const int HEADS = isW2 ? 1 : 8;
    const int kk = t >> 7;
    const int c  = t & 127;
    const int k  = ((b - (isW2 ? 96 : 32)) << 1) + kk;
    const float wv = W[k * 128 + c];
    wt[c * 128 + k] = f2bf(wv);
    ss[kk][c] = wv * as[c];
    sd[kk][c] = wv * ad[c];
    __syncthreads();
    if (c < 16) {
      const int C = 128 / HEADS;
      const int h = (c < 8) ? c : c - 8;
      float s = 0.f;
      if (h < HEADS) {
        const float* sb = (c < 8) ? ss[kk] : sd[kk];
        for (int j = 0; j < C; ++j) s += sb[h * C + j];
      }
      vt[c * 128 + k] = f2bf(s);
    }
  } else if (b == 160) {
    if (t < 8) {
      float s = 0.f;
      for (int m = 0; m < 64; ++m) { const float v = mu[t * 64 + m]; s += v * v; }
      msq[t] = fmaxf(sqrtf(s), 1e-8f);
    }
    __syncthreads();
    #pragma unroll
    for (int p = 0; p < 4; ++p) {
      const int idx = t + p * 256;
      const int j = idx >> 3, k = idx & 7;
      float s = 0.f;
      for (int m = 0; m < 64; ++m) s += mu[k * 64 + m] * g[(size_t)j * 512 + k * 64 + m];
      gmt[k * 128 + j] = f2bf(s / msq[k]);
      gmt[(8 + (idx >> 7)) * 128 + (idx & 127)] = 0;
    }
  } else {
    // deg_count: XCD-windowed counting (deg pre-zeroed by memset)
    const int bb = b - 161;
    const int grp = bb & 3;
    const int lo = (int)(((long long)n * grp) >> 2);
    const int hi = (int)(((long long)n * (grp + 1)) >> 2);
    const int tid = (bb >> 2) * blockDim.x + t;
    const int stride = (NSCAT >> 2) * blockDim.x;
    for (int i = tid; i < E; i += stride) {
      const int d = edst[i];
      if (d >= lo && d < hi) atomicAdd(&deg[d], 1);
    }
  }
}

// ---------------- scans ----------------
__global__ void __launch_bounds__(256)
scan1_kernel(const int* __restrict__ deg, int* __restrict__ out,
             int* __restrict__ blksum, int n) {
  __shared__ int ts[256];
  const int t = threadIdx.x;
  const int base = blockIdx.x * 2048 + t * 8;
  int v[8]; int s = 0;
  #pragma unroll
  for (int i = 0; i < 8; ++i) {
    int x = (base + i < n) ? deg[base + i] + 1 : 0;   // +1 = self-loop
    v[i] = s; s += x;
  }
  ts[t] = s;
  __syncthreads();
  for (int off = 1; off < 256; off <<= 1) {
    int add = (t >= off) ? ts[t - off] : 0;
    __syncthreads();
    ts[t] += add;
    __syncthreads();
  }
  const int excl = ts[t] - s;
  #pragma unroll
  for (int i = 0; i < 8; ++i)
    if (base + i < n) out[base + i] = excl + v[i];
  if (t == 255) blksum[blockIdx.x] = ts[255];
}

__global__ void scan2_kernel(int* __restrict__ blksum, int nb) {
  const int t = threadIdx.x;
  int v = (t < nb) ? blksum[t] : 0;
  #pragma unroll
  for (int off = 1; off < 64; off <<= 1) {
    int u = __shfl_up(v, off);
    if (t >= off) v += u;
  }
  if (t < nb) blksum[t] = v;
}

__global__ void scan3_kernel(int* __restrict__ out, const int* __restrict__ blksum, int n) {
  int i = blockIdx.x * blockDim.x + threadIdx.x;
  if (i >= n) return;
  int b = i >> 11;
  if (b > 0) out[i] += blksum[b - 1];
}

// ---------------- scatter body (XCD-windowed) ----------------
__device__ __forceinline__ void scatter_body(int bidx, const int* __restrict__ esrc,
                                             const int* __restrict__ edst,
                                             int* __restrict__ rowptr, int* __restrict__ col,
                                             int E, int n, int tl) {
  const int grp = bidx & 3;
  const int lo = (int)(((long long)n * grp) >> 2);
  const int hi = (int)(((long long)n * (grp + 1)) >> 2);
  const int tid = (bidx >> 2) * 256 + tl;
  const int stride = (NSCAT >> 2) * 256;
  const int Etot = E + n;
  for (int i = tid; i < Etot; i += stride) {
    int s, d;
    if (i < E) { s = esrc[i]; d = edst[i]; } else { s = d = i - E; }
    if (d >= lo && d < hi) {
      int p = atomicAdd(&rowptr[d], 1);
      col[p] = s;
    }
  }
}

// ---------------- features + attention dots body (bf16 MFMA) ----------------
template<int HEADS, bool BF16IN, bool I8OUT>
__device__ __forceinline__ void
feat_body(int bidx, const void* __restrict__ In_, const unsigned short* __restrict__ wt,
          const unsigned short* __restrict__ vt, const float* __restrict__ bias_in,
          void* __restrict__ Hout_, float* __restrict__ hscale,
          float* __restrict__ a_src, float* __restrict__ a_dst, int n)
{
  __shared__ unsigned short xs[64][136];
  const int t = threadIdx.x;
  const int w = t >> 6, lane = t & 63;
  const int l15 = lane & 15, lg = lane >> 4;
  const int nbase = bidx << 6;

  {
    const int r = t >> 2;
    const int c0s = (t & 3) << 5;
    const int node = nbase + r;
    if (BF16IN) {
      const unsigned short* In2 = (const unsigned short*)In_;
      #pragma unroll
      for (int i = 0; i < 4; ++i) {
        unsigned short pk[8];
        if (node < n) {
          short8 v = *(const short8*)&In2[(size_t)node * 128 + c0s + i * 8];
          #pragma unroll
          for (int j = 0; j < 8; ++j) {
            float f = bf2f((unsigned short)v[j]) + bias_in[c0s + i * 8 + j];
            pk[j] = f2bf(lrelu(f, 0.01f));
          }
        } else {
          #pragma unroll
          for (int j = 0; j < 8; ++j) pk[j] = 0;
        }
        *(short8*)&xs[r][c0s + i * 8] = *(short8*)pk;
      }
    } else {
      const float* In1 = (const float*)In_;
      #pragma unroll
      for (int i = 0; i < 8; ++i) {
        unsigned short pk[4];
        if (node < n) {
          float4 v = *(const float4*)&In1[(size_t)node * 128 + c0s + i * 4];
          pk[0] = f2bf(v.x); pk[1] = f2bf(v.y); pk[2] = f2bf(v.z); pk[3] = f2bf(v.w);
        } else { pk[0] = pk[1] = pk[2] = pk[3] = 0; }
        *(uint2*)&xs[r][c0s + i * 4] = *(uint2*)pk;
      }
    }
  }
  __syncthreads();

  short8 afr[4];
  #pragma unroll
  for (int kc = 0; kc < 4; ++kc)
    afr[kc] = *(const short8*)&xs[w * 16 + l15][kc * 32 + lg * 8];

  const unsigned short* bp[9];
  #pragma unroll
  for (int ct = 0; ct < 8; ++ct)
    bp[ct] = wt + (size_t)(ct * 16 + l15) * 128 + lg * 8;
  bp[8] = vt + (size_t)l15 * 128 + lg * 8;

  f32x4 acc[9];
  #pragma unroll
  for (int ct = 0; ct < 9; ++ct) acc[ct] = (f32x4){0.f, 0.f, 0.f, 0.f};

  short8 bcur[9], bnxt[9];
  #pragma unroll
  for (int ct = 0; ct < 9; ++ct) bcur[ct] = *(const short8*)bp[ct];

  #pragma unroll
  for (int kc = 0; kc < 4; ++kc) {
    if (kc < 3) {
      #pragma unroll
      for (int ct = 0; ct < 9; ++ct)
        bnxt[ct] = *(const short8*)(bp[ct] + (kc + 1) * 32);
    }
    #pragma unroll
    for (int ct = 0; ct < 9; ++ct)
      acc[ct] = __builtin_amdgcn_mfma_f32_16x16x32_bf16(afr[kc], bcur[ct], acc[ct], 0, 0, 0);
    if (kc < 3) {
      #pragma unroll
      for (int ct = 0; ct < 9; ++ct) bcur[ct] = bnxt[ct];
    }
  }
  __syncthreads();   // afr reads done before xs reuse

  if (I8OUT) {
    unsigned char* xb = (unsigned char*)xs;      // row stride 272 B (16B-aligned)
    float inv127[4], scl[4];
    #pragma unroll
    for (int r = 0; r < 4; ++r) {
      float m = 0.f;
      #pragma unroll
      for (int ct = 0; ct < 8; ++ct) m = fmaxf(m, fabsf(acc[ct][r]));
      m = fmaxf(m, __shfl_xor(m, 1));
      m = fmaxf(m, __shfl_xor(m, 2));
      m = fmaxf(m, __shfl_xor(m, 4));
      m = fmaxf(m, __shfl_xor(m, 8));
      m = fmaxf(m, 1e-12f);
      inv127[r] = 127.f / m;
      scl[r] = m * (1.f / 127.f);
    }
    #pragma unroll
    for (int ct = 0; ct < 8; ++ct)
      #pragma unroll
      for (int r = 0; r < 4; ++r) {
        const int q = __float2int_rn(acc[ct][r] * inv127[r]);
        xb[(w * 16 + lg * 4 + r) * 272 + ct * 16 + l15] = (unsigned char)q;
      }
    if (l15 == 0) {
      #pragma unroll
      for (int r = 0; r < 4; ++r) {
        const int node = nbase + w * 16 + lg * 4 + r;
        if (node < n) hscale[node] = scl[r];
      }
    }
    __syncthreads();
    {
      const int rr = t >> 2;
      const int cc = (t & 3) * 32;
      const int node = nbase + rr;
      if (node < n) {
        unsigned char* H8 = (unsigned char*)Hout_;
        *(uint4*)&H8[(size_t)node * 128 + cc]      = *(const uint4*)&xb[rr * 272 + cc];
        *(uint4*)&H8[(size_t)node * 128 + cc + 16] = *(const uint4*)&xb[rr * 272 + cc + 16];
      }
    }
  } else {
    #pragma unroll
    for (int ct = 0; ct < 8; ++ct)
      #pragma unroll
      for (int r = 0; r < 4; ++r)
        xs[w * 16 + lg * 4 + r][ct * 16 + l15] = f2bf(acc[ct][r]);
    __syncthreads();
    {
      const int r = t >> 2;
      const int c0s = (t & 3) << 5;
      const int node = nbase + r;
      if (node < n) {
        unsigned short* Hb = (unsigned short*)Hout_;
        #pragma unroll
        for (int i = 0; i < 4; ++i)
          *(short8*)&Hb[(size_t)node * 128 + c0s + i * 8] = *(const short8*)&xs[r][c0s + i * 8];
      }
    }
  }

  #pragma unroll
  for (int r = 0; r < 4; ++r) {
    const int node = nbase + w * 16 + lg * 4 + r;
    if (node < n) {
      const float v = acc[8][r];
      if (HEADS == 8) {
        if (l15 < 8) a_src[node * 8 + l15] = v;
        else         a_dst[node * 8 + (l15 - 8)] = v;
      } else {
        if (l15 == 0) a_src[node] = v;
        else if (l15 == 8) a_dst[node] = v;
      }
    }
  }
}

// ---------------- fused scatter + feat1 ----------------
// blocks [0, NSCAT): scatter; blocks [NSCAT, ...): feat1 (heads=8, f32 in, int8 out)
__global__ void __launch_bounds__(256)
scatter_feat1_kernel(const int* __restrict__ esrc, const int* __restrict__ edst,
                     int* __restrict__ rowptr, int* __restrict__ col, int E,
                     const float* __restrict__ x, const unsigned short* __restrict__ wt1,
                     const unsigned short* __restrict__ vt1,
                     void* __restrict__ Hout, float* __restrict__ hscale,
                     float* __restrict__ a_src, float* __restrict__ a_dst, int n)
{
  if (blockIdx.x < NSCAT) {
    scatter_body(blockIdx.x, esrc, edst, rowptr, col, E, n, threadIdx.x);
  } else {
    feat_body<8, false, true>(blockIdx.x - NSCAT, x, wt1, vt1, nullptr,
                              Hout, hscale, a_src, a_dst, n);
  }
}

// ---------------- standalone feat2 ----------------
__global__ void __launch_bounds__(256)
feat2_kernel(const void* __restrict__ In_, const unsigned short* __restrict__ wt,
             const unsigned short* __restrict__ vt, const float* __restrict__ bias_in,
             void* __restrict__ Hout_, float* __restrict__ a_src,
             float* __restrict__ a_dst, int n)
{
  feat_body<1, true, false>(blockIdx.x, In_, wt, vt, bias_in, Hout_, nullptr, a_src, a_dst, n);
}

// ---------------- CSR gather-aggregate (8-deep pipelined; H int8+scale or bf16) ----------------
template<int HEADS, bool I8H>
__global__ void __launch_bounds__(256)
agg_csr_kernel(const int* __restrict__ rowptr_end, const int* __restrict__ col,
               const float* __restrict__ a_src, const float* __restrict__ a_dst,
               const void* __restrict__ Hf_, const float* __restrict__ hscale,
               unsigned int* __restrict__ agg, int n)
{
  const int wave = threadIdx.x >> 6;
  const int lane = threadIdx.x & 63;
  const int d = blockIdx.x * 4 + wave;
  if (d >= n) return;
  const int beg = (d == 0) ? 0 : rowptr_end[d - 1];
  const int end = rowptr_end[d];

  const int ei = lane >> 3;
  const int hh = (HEADS == 8) ? (lane & 7) : 0;
  const int bh = (HEADS == 8) ? (lane >> 3) : 0;
  const float adv = (HEADS == 8) ? a_dst[d * 8 + hh] : a_dst[d];
  const unsigned int* Hu = (const unsigned int*)Hf_;
  const unsigned short* H16 = (const unsigned short*)Hf_;

  float accx = 0.f, accy = 0.f, sum = 0.f;
  const int nb8 = (end - beg) >> 3;
  int sv = 0; float a = 0.f, Sv = 0.f;
  if (nb8 > 0) {
    sv = col[beg + ei];
    a = __expf(lrelu(a_src[sv * HEADS + hh] + adv, 0.2f));
    if (I8H) Sv = hscale[sv];
    if (HEADS == 8 || (lane & 7) == 0) sum += a;
  }
  for (int b = 0; b < nb8; ++b) {
    int s[8]; float al[8];
    #pragma unroll
    for (int e = 0; e < 8; ++e) {
      s[e]  = __shfl(sv, e * 8);
      al[e] = __shfl(a, e * 8 + bh);
      if (I8H) al[e] *= __shfl(Sv, e * 8);
    }
    unsigned int hv[8];
    if (I8H) {
      #pragma unroll
      for (int e = 0; e < 8; ++e) hv[e] = H16[(size_t)s[e] * 64 + lane];
    } else {
      #pragma unroll
      for (int e = 0; e < 8; ++e) hv[e] = Hu[(size_t)s[e] * 64 + lane];
    }
    if (b + 1 < nb8) {   // prefetch next batch under the gather latency
      sv = col[beg + ((b + 1) << 3) + ei];
      a = __expf(lrelu(a_src[sv * HEADS + hh] + adv, 0.2f));
      if (I8H) Sv = hscale[sv];
      if (HEADS == 8 || (lane & 7) == 0) sum += a;
    }
    #pragma unroll
    for (int e = 0; e < 8; ++e) {
      if (I8H) {
        const int wv = (int)hv[e];
        accx += al[e] * (float)((wv << 24) >> 24);
        accy += al[e] * (float)((wv << 16) >> 24);
      } else {
        accx += al[e] * __uint_as_float(hv[e] << 16);
        accy += al[e] * __uint_as_float(hv[e] & 0xffff0000u);
      }
    }
  }
  {
    const int p0 = beg + (nb8 << 3);
    const int cnt = end - p0;
    if (cnt > 0) {
      int svt = 0; float at = 0.f, Svt = 0.f;
      if (ei < cnt) {
        svt = col[p0 + ei];
        at = __expf(lrelu(a_src[svt * HEADS + hh] + adv, 0.2f));
        if (I8H) Svt = hscale[svt];
        if (HEADS == 8 || (lane & 7) == 0) sum += at;
      }
      for (int e = 0; e < cnt; ++e) {
        float al = __shfl(at, e * 8 + bh);
        if (I8H) al *= __shfl(Svt, e * 8);
        const int sx = __shfl(svt, e * 8);
        if (I8H) {
          const int wv = (int)H16[(size_t)sx * 64 + lane];
          accx += al * (float)((wv << 24) >> 24);
          accy += al * (float)((wv << 16) >> 24);
        } else {
          const unsigned int hv = Hu[(size_t)sx * 64 + lane];
          accx += al * __uint_as_float(hv << 16);
          accy += al * __uint_as_float(hv & 0xffff0000u);
        }
      }
    }
  }
  sum += __shfl_xor(sum, 8);
  sum += __shfl_xor(sum, 16);
  sum += __shfl_xor(sum, 32);
  const float denom = __shfl(sum, bh) + 1e-16f;
  const float inv = 1.f / denom;
  agg[(size_t)d * 64 + lane] = (unsigned int)f2bf(accx * inv) | ((unsigned int)f2bf(accy * inv) << 16);
}

// ---------------- h@g + cosine vs mu (bf16 MFMA, 32-node tiles, gm'-tile epilogue) ----------------
__global__ void __launch_bounds__(256)
final_kernel(const unsigned short* __restrict__ agg2b, const float* __restrict__ b2,
             const unsigned short* __restrict__ gt, const unsigned short* __restrict__ gmt,
             float* __restrict__ outp, int n)
{
  __shared__ unsigned short os[32][136];
  const int t = threadIdx.x;
  const int w = t >> 6;
  const int lane = t & 63;
  const int l15 = lane & 15;
  const int lg = lane >> 4;
  const int nbase = blockIdx.x << 5;

  {
    const int r = t >> 3;
    const int c = (t & 7) * 16;
    const int node = nbase + r;
    unsigned short pk[16];
    if (node < n) {
      short8 v0 = *(const short8*)&agg2b[(size_t)node * 128 + c];
      short8 v1 = *(const short8*)&agg2b[(size_t)node * 128 + c + 8];
      #pragma unroll
      for (int j = 0; j < 8; ++j) pk[j]     = f2bf(bf2f((unsigned short)v0[j]) + b2[c + j]);
      #pragma unroll
      for (int j = 0; j < 8; ++j) pk[8 + j] = f2bf(bf2f((unsigned short)v1[j]) + b2[c + 8 + j]);
    } else {
      #pragma unroll
      for (int i = 0; i < 16; ++i) pk[i] = 0;
    }
    *(short8*)&os[r][c]     = *(short8*)&pk[0];
    *(short8*)&os[r][c + 8] = *(short8*)&pk[8];
  }
  __syncthreads();

  short8 afr[2][4];
  #pragma unroll
  for (int rt = 0; rt < 2; ++rt)
    #pragma unroll
    for (int kc = 0; kc < 4; ++kc)
      afr[rt][kc] = *(const short8*)&os[rt * 16 + l15][kc * 32 + lg * 8];

  const unsigned short* gw  = gt  + (size_t)(w * 128 + l15) * 128 + lg * 8;
  const unsigned short* gmw = gmt + (size_t)l15 * 128 + lg * 8;

  f32x4 acc[2][8];
  f32x4 accg[2];
  #pragma unroll
  for (int rt = 0; rt < 2; ++rt) {
    #pragma unroll
    for (int ct = 0; ct < 8; ++ct)
      acc[rt][ct] = (f32x4){0.f, 0.f, 0.f, 0.f};
    accg[rt] = (f32x4){0.f, 0.f, 0.f, 0.f};
  }

  short8 bcur[9], bnxt[9];
  #pragma unroll
  for (int ct = 0; ct < 8; ++ct)
    bcur[ct] = *(const short8*)&gw[(size_t)ct * 2048];
  bcur[8] = *(const short8*)gmw;

  #pragma unroll
  for (int kc = 0; kc < 4; ++kc) {
    if (kc < 3) {
      #pragma unroll
      for (int ct = 0; ct < 8; ++ct)
        bnxt[ct] = *(const short8*)&gw[(size_t)ct * 2048 + (kc + 1) * 32];
      bnxt[8] = *(const short8*)(gmw + (kc + 1) * 32);
    }
    #pragma unroll
    for (int ct = 0; ct < 8; ++ct) {
      acc[0][ct] = __builtin_amdgcn_mfma_f32_16x16x32_bf16(afr[0][kc], bcur[ct], acc[0][ct], 0, 0, 0);
      acc[1][ct] = __builtin_amdgcn_mfma_f32_16x16x32_bf16(afr[1][kc], bcur[ct], acc[1][ct], 0, 0, 0);
    }
    accg[0] = __builtin_amdgcn_mfma_f32_16x16x32_bf16(afr[0][kc], bcur[8], accg[0], 0, 0, 0);
    accg[1] = __builtin_amdgcn_mfma_f32_16x16x32_bf16(afr[1][kc], bcur[8], accg[1], 0, 0, 0);
    if (kc < 3) {
      #pragma unroll
      for (int ct = 0; ct < 9; ++ct) bcur[ct] = bnxt[ct];
    }
  }

  const int k0 = w * 2, k1 = w * 2 + 1;
  #pragma unroll
  for (int rt = 0; rt < 2; ++rt) {
    float ss0[4] = {0.f, 0.f, 0.f, 0.f};
    float ss1[4] = {0.f, 0.f, 0.f, 0.f};
    #pragma unroll
    for (int ct = 0; ct < 4; ++ct) {
      const f32x4 a = acc[rt][ct];
      const f32x4 b = acc[rt][4 + ct];
      #pragma unroll
      for (int r = 0; r < 4; ++r) {
        ss0[r] += a[r] * a[r];
        ss1[r] += b[r] * b[r];
      }
    }
    #pragma unroll
    for (int r = 0; r < 4; ++r) {
      ss0[r] += __shfl_xor(ss0[r], 1); ss1[r] += __shfl_xor(ss1[r], 1);
      ss0[r] += __shfl_xor(ss0[r], 2); ss1[r] += __shfl_xor(ss1[r], 2);
      ss0[r] += __shfl_xor(ss0[r], 4); ss1[r] += __shfl_xor(ss1[r], 4);
      ss0[r] += __shfl_xor(ss0[r], 8); ss1[r] += __shfl_xor(ss1[r], 8);
    }
    #pragma unroll
    for (int r = 0; r < 4; ++r) {
      const int node = nbase + rt * 16 + lg * 4 + r;
      if (node < n) {
        const float nv = accg[rt][r];
        if (l15 == k0)      outp[(size_t)node * 8 + k0] = nv / fmaxf(sqrtf(ss0[r]), 1e-8f);
        else if (l15 == k1) outp[(size_t)node * 8 + k1] = nv / fmaxf(sqrtf(ss1[r]), 1e-8f);
      }
    }
  }
}

extern "C" void kernel_launch(void* const* d_in, const int* in_sizes, int n_in,
                              void* d_out, int out_size, void* d_ws, size_t ws_size,
                              hipStream_t stream)
{
  const float* x   = (const float*)d_in[0];
  const int*   eix = (const int*)d_in[1];
  const float* W1  = (const float*)d_in[2];
  const float* as1 = (const float*)d_in[3];
  const float* ad1 = (const float*)d_in[4];
  const float* b1  = (const float*)d_in[5];
  const float* W2  = (const float*)d_in[6];
  const float* as2 = (const float*)d_in[7];
  const float* ad2 = (const float*)d_in[8];
  const float* b2  = (const float*)d_in[9];
  const float* g   = (const float*)d_in[10];
  const float* mu  = (const float*)d_in[11];
  float* outp = (float*)d_out;

  const int n    = in_sizes[0] / 128;
  const int E    = in_sizes[1] / 2;
  const int* esrc = eix;
  const int* edst = eix + E;

  unsigned short* hb  = (unsigned short*)d_ws;   // H1 int8 (128B/row) or H2 bf16 (256B/row)
  unsigned short* gt  = hb + (size_t)n * 128;
  unsigned short* wt1 = gt + 512 * 128;
  unsigned short* vt1 = wt1 + 128 * 128;
  unsigned short* wt2 = vt1 + 16 * 128;
  unsigned short* vt2 = wt2 + 128 * 128;
  unsigned short* gmt = vt2 + 16 * 128;
  unsigned short* agg_b = (unsigned short*)((char*)d_ws + (size_t)n * 512);
  float* asrc   = (float*)((char*)d_ws + (size_t)n * 1024);
  float* adst   = asrc + (size_t)n * 8;
  int*   rowptr = (int*)(adst + (size_t)n * 8);
  int*   col    = rowptr + n;
  float* hscale = (float*)(col + (size_t)E + n);
  int*   deg    = (int*)agg_b;
  int*   blksum = deg + n;

  // ---------------- deg zero, then fused prep + deg_count ----------------
  hipMemsetAsync(deg, 0, (size_t)n * sizeof(int), stream);
  prep_kernel<<<161 + NSCAT, 256, 0, stream>>>(g, gt, W1, as1, ad1, wt1, vt1,
                                               W2, as2, ad2, wt2, vt2, mu, gmt,
                                               edst, deg, E, n);

  // ---------------- scans ----------------
  const int nb = (n + 2047) / 2048;
  scan1_kernel<<<nb, 256, 0, stream>>>(deg, rowptr, blksum, n);
  scan2_kernel<<<1, 64, 0, stream>>>(blksum, nb);
  scan3_kernel<<<(n + 255) / 256, 256, 0, stream>>>(rowptr, blksum, n);

  // ---------------- fused scatter + feat1 (independent work overlapped) ----------------
  const int nfeat = (n + 63) / 64;
  scatter_feat1_kernel<<<NSCAT + nfeat, 256, 0, stream>>>(
      esrc, edst, rowptr, col, E, x, wt1, vt1, hb, hscale, asrc, adst, n);

  // ---------------- conv1 aggregate (H int8 + per-row scale) ----------------
  agg_csr_kernel<8, true><<<(n + 3) / 4, 256, 0, stream>>>(
      rowptr, col, asrc, adst, hb, hscale, (unsigned int*)agg_b, n);

  // ---------------- conv2 (heads=1, C=128): H in bf16 ----------------
  feat2_kernel<<<nfeat, 256, 0, stream>>>(agg_b, wt2, vt2, b1, hb, asrc, adst, n);
  agg_csr_kernel<1, false><<<(n + 3) / 4, 256, 0, stream>>>(
      rowptr, col, asrc, adst, hb, nullptr, (unsigned int*)agg_b, n);

  // ---------------- h@g + cosine vs mu ----------------
  final_kernel<<<(n + 31) / 32, 256, 0, stream>>>(agg_b, b2, gt, gmt, outp, n);
}

// Round 15
// 460.267 us; speedup vs baseline: 1.0860x; 1.0157x over previous
//
#include <hip/hip_runtime.h>
#include <hip/hip_bf16.h>

typedef short short8 __attribute__((ext_vector_type(8)));
typedef float f32x4 __attribute__((ext_vector_type(4)));

__device__ __forceinline__ float lrelu(float x, float s) { return x > 0.f ? x : x * s; }

__device__ __forceinline__ unsigned short f2bf(float x) {
  union { __hip_bfloat16 b; unsigned short u; } cv;
  cv.b = __float2bfloat16(x);
  return cv.u;
}
__device__ __forceinline__ float bf2f(unsigned short u) {
  return __uint_as_float(((unsigned int)u) << 16);
}

#define NSCAT 2048

// ---------------- unified param prep + deg_count ----------------
// blocks 0..31: g -> gt ; 32..95: W1 ; 96..159: W2 ; 160: gm' ; 161..: deg_count
__global__ void __launch_bounds__(256)
prep_kernel(const float* __restrict__ g, unsigned short* __restrict__ gt,
            const float* __restrict__ W1, const float* __restrict__ as1,
            const float* __restrict__ ad1, unsigned short* __restrict__ wt1,
            unsigned short* __restrict__ vt1,
            const float* __restrict__ W2, const float* __restrict__ as2,
            const float* __restrict__ ad2, unsigned short* __restrict__ wt2,
            unsigned short* __restrict__ vt2,
            const float* __restrict__ mu, unsigned short* __restrict__ gmt,
            const int* __restrict__ edst, int* __restrict__ deg, int E, int n)
{
  __shared__ float ts[32][68];
  __shared__ float ss[2][128], sd[2][128];
  __shared__ float msq[8];
  const int b = blockIdx.x;
  const int t = threadIdx.x;
  if (b < 32) {
    const int kb = (b >> 3) * 32;
    const int cb = (b & 7) * 64;
    {
      const int r = t >> 3;
      const int c = (t & 7) * 8;
      float4 v0 = *(const float4*)&g[(size_t)(kb + r) * 512 + cb + c];
      float4 v1 = *(const float4*)&g[(size_t)(kb + r) * 512 + cb + c + 4];
      *(float4*)&ts[r][c] = v0;
      *(float4*)&ts[r][c + 4] = v1;
    }
    __syncthreads();
    {
      const int c = t >> 2;
      const int k0 = (t & 3) * 8;
      unsigned short pk[8];
      #pragma unroll
      for (int j = 0; j < 8; ++j) pk[j] = f2bf(ts[k0 + j][c]);
      *(short8*)&gt[(size_t)(cb + c) * 128 + kb + k0] = *(short8*)pk;
    }
  } else if (b < 160) {
    const int isW2 = (b >= 96) ? 1 : 0;
    const float* W  = isW2 ? W2 : W1;
    const float* as = isW2 ? as2 : as1;
    const float* ad = isW2 ? ad2 : ad1;
    unsigned short* wt = isW2 ? wt2 : wt1;
    unsigned short* vt = isW2 ? vt2 : vt1;
    const int HEADS = isW2 ? 1 : 8;
    const int kk = t >> 7;
    const int c  = t & 127;
    const int k  = ((b - (isW2 ? 96 : 32)) << 1) + kk;
    const float wv = W[k * 128 + c];
    wt[c * 128 + k] = f2bf(wv);
    ss[kk][c] = wv * as[c];
    sd[kk][c] = wv * ad[c];
    __syncthreads();
    if (c < 16) {
      const int C = 128 / HEADS;
      const int h = (c < 8) ? c : c - 8;
      float s = 0.f;
      if (h < HEADS) {
        const float* sb = (c < 8) ? ss[kk] : sd[kk];
        for (int j = 0; j < C; ++j) s += sb[h * C + j];
      }
      vt[c * 128 + k] = f2bf(s);
    }
  } else if (b == 160) {
    if (t < 8) {
      float s = 0.f;
      for (int m = 0; m < 64; ++m) { const float v = mu[t * 64 + m]; s += v * v; }
      msq[t] = fmaxf(sqrtf(s), 1e-8f);
    }
    __syncthreads();
    #pragma unroll
    for (int p = 0; p < 4; ++p) {
      const int idx = t + p * 256;
      const int j = idx >> 3, k = idx & 7;
      float s = 0.f;
      for (int m = 0; m < 64; ++m) s += mu[k * 64 + m] * g[(size_t)j * 512 + k * 64 + m];
      gmt[k * 128 + j] = f2bf(s / msq[k]);
      gmt[(8 + (idx >> 7)) * 128 + (idx & 127)] = 0;
    }
  } else {
    // deg_count: 8 windows, one per XCD (bid%8 -> XCD); deg pre-zeroed by memset
    const int bb = b - 161;
    const int grp = bb & 7;
    const int lo = (int)(((long long)n * grp) >> 3);
    const int hi = (int)(((long long)n * (grp + 1)) >> 3);
    const int tid = (bb >> 3) * blockDim.x + t;
    const int stride = (NSCAT >> 3) * blockDim.x;
    for (int i = tid; i < E; i += stride) {
      const int d = edst[i];
      if (d >= lo && d < hi) atomicAdd(&deg[d], 1);
    }
  }
}

// ---------------- scans ----------------
__global__ void __launch_bounds__(256)
scan1_kernel(const int* __restrict__ deg, int* __restrict__ out,
             int* __restrict__ blksum, int n) {
  __shared__ int ts[256];
  const int t = threadIdx.x;
  const int base = blockIdx.x * 2048 + t * 8;
  int v[8]; int s = 0;
  #pragma unroll
  for (int i = 0; i < 8; ++i) {
    int x = (base + i < n) ? deg[base + i] + 1 : 0;   // +1 = self-loop
    v[i] = s; s += x;
  }
  ts[t] = s;
  __syncthreads();
  for (int off = 1; off < 256; off <<= 1) {
    int add = (t >= off) ? ts[t - off] : 0;
    __syncthreads();
    ts[t] += add;
    __syncthreads();
  }
  const int excl = ts[t] - s;
  #pragma unroll
  for (int i = 0; i < 8; ++i)
    if (base + i < n) out[base + i] = excl + v[i];
  if (t == 255) blksum[blockIdx.x] = ts[255];
}

__global__ void scan2_kernel(int* __restrict__ blksum, int nb) {
  const int t = threadIdx.x;
  int v = (t < nb) ? blksum[t] : 0;
  #pragma unroll
  for (int off = 1; off < 64; off <<= 1) {
    int u = __shfl_up(v, off);
    if (t >= off) v += u;
  }
  if (t < nb) blksum[t] = v;
}

__global__ void scan3_kernel(int* __restrict__ out, const int* __restrict__ blksum, int n) {
  int i = blockIdx.x * blockDim.x + threadIdx.x;
  if (i >= n) return;
  int b = i >> 11;
  if (b > 0) out[i] += blksum[b - 1];
}

// ---------------- scatter body (8 XCD-local windows) ----------------
__device__ __forceinline__ void scatter_body(int bidx, const int* __restrict__ esrc,
                                             const int* __restrict__ edst,
                                             int* __restrict__ rowptr, int* __restrict__ col,
                                             int E, int n, int tl) {
  const int grp = bidx & 7;
  const int lo = (int)(((long long)n * grp) >> 3);
  const int hi = (int)(((long long)n * (grp + 1)) >> 3);
  const int tid = (bidx >> 3) * 256 + tl;
  const int stride = (NSCAT >> 3) * 256;
  const int Etot = E + n;
  for (int i = tid; i < Etot; i += stride) {
    int s, d;
    if (i < E) { s = esrc[i]; d = edst[i]; } else { s = d = i - E; }
    if (d >= lo && d < hi) {
      int p = atomicAdd(&rowptr[d], 1);
      col[p] = s;
    }
  }
}

// ---------------- features + attention dots body (bf16 MFMA) ----------------
template<int HEADS, bool BF16IN, bool I8OUT>
__device__ __forceinline__ void
feat_body(int bidx, const void* __restrict__ In_, const unsigned short* __restrict__ wt,
          const unsigned short* __restrict__ vt, const float* __restrict__ bias_in,
          void* __restrict__ Hout_, float* __restrict__ hscale,
          float* __restrict__ a_src, float* __restrict__ a_dst, int n)
{
  __shared__ unsigned short xs[64][136];
  const int t = threadIdx.x;
  const int w = t >> 6, lane = t & 63;
  const int l15 = lane & 15, lg = lane >> 4;
  const int nbase = bidx << 6;

  {
    const int r = t >> 2;
    const int c0s = (t & 3) << 5;
    const int node = nbase + r;
    if (BF16IN) {
      const unsigned short* In2 = (const unsigned short*)In_;
      #pragma unroll
      for (int i = 0; i < 4; ++i) {
        unsigned short pk[8];
        if (node < n) {
          short8 v = *(const short8*)&In2[(size_t)node * 128 + c0s + i * 8];
          #pragma unroll
          for (int j = 0; j < 8; ++j) {
            float f = bf2f((unsigned short)v[j]) + bias_in[c0s + i * 8 + j];
            pk[j] = f2bf(lrelu(f, 0.01f));
          }
        } else {
          #pragma unroll
          for (int j = 0; j < 8; ++j) pk[j] = 0;
        }
        *(short8*)&xs[r][c0s + i * 8] = *(short8*)pk;
      }
    } else {
      const float* In1 = (const float*)In_;
      #pragma unroll
      for (int i = 0; i < 8; ++i) {
        unsigned short pk[4];
        if (node < n) {
          float4 v = *(const float4*)&In1[(size_t)node * 128 + c0s + i * 4];
          pk[0] = f2bf(v.x); pk[1] = f2bf(v.y); pk[2] = f2bf(v.z); pk[3] = f2bf(v.w);
        } else { pk[0] = pk[1] = pk[2] = pk[3] = 0; }
        *(uint2*)&xs[r][c0s + i * 4] = *(uint2*)pk;
      }
    }
  }
  __syncthreads();

  short8 afr[4];
  #pragma unroll
  for (int kc = 0; kc < 4; ++kc)
    afr[kc] = *(const short8*)&xs[w * 16 + l15][kc * 32 + lg * 8];

  const unsigned short* bp[9];
  #pragma unroll
  for (int ct = 0; ct < 8; ++ct)
    bp[ct] = wt + (size_t)(ct * 16 + l15) * 128 + lg * 8;
  bp[8] = vt + (size_t)l15 * 128 + lg * 8;

  f32x4 acc[9];
  #pragma unroll
  for (int ct = 0; ct < 9; ++ct) acc[ct] = (f32x4){0.f, 0.f, 0.f, 0.f};

  short8 bcur[9], bnxt[9];
  #pragma unroll
  for (int ct = 0; ct < 9; ++ct) bcur[ct] = *(const short8*)bp[ct];

  #pragma unroll
  for (int kc = 0; kc < 4; ++kc) {
    if (kc < 3) {
      #pragma unroll
      for (int ct = 0; ct < 9; ++ct)
        bnxt[ct] = *(const short8*)(bp[ct] + (kc + 1) * 32);
    }
    #pragma unroll
    for (int ct = 0; ct < 9; ++ct)
      acc[ct] = __builtin_amdgcn_mfma_f32_16x16x32_bf16(afr[kc], bcur[ct], acc[ct], 0, 0, 0);
    if (kc < 3) {
      #pragma unroll
      for (int ct = 0; ct < 9; ++ct) bcur[ct] = bnxt[ct];
    }
  }
  __syncthreads();   // afr reads done before xs reuse

  if (I8OUT) {
    unsigned char* xb = (unsigned char*)xs;      // row stride 272 B (16B-aligned)
    float inv127[4], scl[4];
    #pragma unroll
    for (int r = 0; r < 4; ++r) {
      float m = 0.f;
      #pragma unroll
      for (int ct = 0; ct < 8; ++ct) m = fmaxf(m, fabsf(acc[ct][r]));
      m = fmaxf(m, __shfl_xor(m, 1));
      m = fmaxf(m, __shfl_xor(m, 2));
      m = fmaxf(m, __shfl_xor(m, 4));
      m = fmaxf(m, __shfl_xor(m, 8));
      m = fmaxf(m, 1e-12f);
      inv127[r] = 127.f / m;
      scl[r] = m * (1.f / 127.f);
    }
    #pragma unroll
    for (int ct = 0; ct < 8; ++ct)
      #pragma unroll
      for (int r = 0; r < 4; ++r) {
        const int q = __float2int_rn(acc[ct][r] * inv127[r]);
        xb[(w * 16 + lg * 4 + r) * 272 + ct * 16 + l15] = (unsigned char)q;
      }
    if (l15 == 0) {
      #pragma unroll
      for (int r = 0; r < 4; ++r) {
        const int node = nbase + w * 16 + lg * 4 + r;
        if (node < n) hscale[node] = scl[r];
      }
    }
    __syncthreads();
    {
      const int rr = t >> 2;
      const int cc = (t & 3) * 32;
      const int node = nbase + rr;
      if (node < n) {
        unsigned char* H8 = (unsigned char*)Hout_;
        *(uint4*)&H8[(size_t)node * 128 + cc]      = *(const uint4*)&xb[rr * 272 + cc];
        *(uint4*)&H8[(size_t)node * 128 + cc + 16] = *(const uint4*)&xb[rr * 272 + cc + 16];
      }
    }
  } else {
    #pragma unroll
    for (int ct = 0; ct < 8; ++ct)
      #pragma unroll
      for (int r = 0; r < 4; ++r)
        xs[w * 16 + lg * 4 + r][ct * 16 + l15] = f2bf(acc[ct][r]);
    __syncthreads();
    {
      const int r = t >> 2;
      const int c0s = (t & 3) << 5;
      const int node = nbase + r;
      if (node < n) {
        unsigned short* Hb = (unsigned short*)Hout_;
        #pragma unroll
        for (int i = 0; i < 4; ++i)
          *(short8*)&Hb[(size_t)node * 128 + c0s + i * 8] = *(const short8*)&xs[r][c0s + i * 8];
      }
    }
  }

  #pragma unroll
  for (int r = 0; r < 4; ++r) {
    const int node = nbase + w * 16 + lg * 4 + r;
    if (node < n) {
      const float v = acc[8][r];
      if (HEADS == 8) {
        if (l15 < 8) a_src[node * 8 + l15] = v;
        else         a_dst[node * 8 + (l15 - 8)] = v;
      } else {
        if (l15 == 0) a_src[node] = v;
        else if (l15 == 8) a_dst[node] = v;
      }
    }
  }
}

// ---------------- fused scatter + feat1 ----------------
// blocks [0, NSCAT): scatter; blocks [NSCAT, ...): feat1 (heads=8, f32 in, int8 out)
__global__ void __launch_bounds__(256)
scatter_feat1_kernel(const int* __restrict__ esrc, const int* __restrict__ edst,
                     int* __restrict__ rowptr, int* __restrict__ col, int E,
                     const float* __restrict__ x, const unsigned short* __restrict__ wt1,
                     const unsigned short* __restrict__ vt1,
                     void* __restrict__ Hout, float* __restrict__ hscale,
                     float* __restrict__ a_src, float* __restrict__ a_dst, int n)
{
  if (blockIdx.x < NSCAT) {
    scatter_body(blockIdx.x, esrc, edst, rowptr, col, E, n, threadIdx.x);
  } else {
    feat_body<8, false, true>(blockIdx.x - NSCAT, x, wt1, vt1, nullptr,
                              Hout, hscale, a_src, a_dst, n);
  }
}

// ---------------- standalone feat2 ----------------
__global__ void __launch_bounds__(256)
feat2_kernel(const void* __restrict__ In_, const unsigned short* __restrict__ wt,
             const unsigned short* __restrict__ vt, const float* __restrict__ bias_in,
             void* __restrict__ Hout_, float* __restrict__ a_src,
             float* __restrict__ a_dst, int n)
{
  feat_body<1, true, false>(blockIdx.x, In_, wt, vt, bias_in, Hout_, nullptr, a_src, a_dst, n);
}

// ---------------- CSR gather-aggregate (8-deep pipelined; H int8+scale or bf16) ----------------
template<int HEADS, bool I8H>
__global__ void __launch_bounds__(256)
agg_csr_kernel(const int* __restrict__ rowptr_end, const int* __restrict__ col,
               const float* __restrict__ a_src, const float* __restrict__ a_dst,
               const void* __restrict__ Hf_, const float* __restrict__ hscale,
               unsigned int* __restrict__ agg, int n)
{
  const int wave = threadIdx.x >> 6;
  const int lane = threadIdx.x & 63;
  const int d = blockIdx.x * 4 + wave;
  if (d >= n) return;
  const int beg = (d == 0) ? 0 : rowptr_end[d - 1];
  const int end = rowptr_end[d];

  const int ei = lane >> 3;
  const int hh = (HEADS == 8) ? (lane & 7) : 0;
  const int bh = (HEADS == 8) ? (lane >> 3) : 0;
  const float adv = (HEADS == 8) ? a_dst[d * 8 + hh] : a_dst[d];
  const unsigned int* Hu = (const unsigned int*)Hf_;
  const unsigned short* H16 = (const unsigned short*)Hf_;

  float accx = 0.f, accy = 0.f, sum = 0.f;
  const int nb8 = (end - beg) >> 3;
  int sv = 0; float a = 0.f, Sv = 0.f;
  if (nb8 > 0) {
    sv = col[beg + ei];
    a = __expf(lrelu(a_src[sv * HEADS + hh] + adv, 0.2f));
    if (I8H) Sv = hscale[sv];
    if (HEADS == 8 || (lane & 7) == 0) sum += a;
  }
  for (int b = 0; b < nb8; ++b) {
    int s[8]; float al[8];
    #pragma unroll
    for (int e = 0; e < 8; ++e) {
      s[e]  = __shfl(sv, e * 8);
      al[e] = __shfl(a, e * 8 + bh);
      if (I8H) al[e] *= __shfl(Sv, e * 8);
    }
    unsigned int hv[8];
    if (I8H) {
      #pragma unroll
      for (int e = 0; e < 8; ++e) hv[e] = H16[(size_t)s[e] * 64 + lane];
    } else {
      #pragma unroll
      for (int e = 0; e < 8; ++e) hv[e] = Hu[(size_t)s[e] * 64 + lane];
    }
    if (b + 1 < nb8) {   // prefetch next batch under the gather latency
      sv = col[beg + ((b + 1) << 3) + ei];
      a = __expf(lrelu(a_src[sv * HEADS + hh] + adv, 0.2f));
      if (I8H) Sv = hscale[sv];
      if (HEADS == 8 || (lane & 7) == 0) sum += a;
    }
    #pragma unroll
    for (int e = 0; e < 8; ++e) {
      if (I8H) {
        const int wv = (int)hv[e];
        accx += al[e] * (float)((wv << 24) >> 24);
        accy += al[e] * (float)((wv << 16) >> 24);
      } else {
        accx += al[e] * __uint_as_float(hv[e] << 16);
        accy += al[e] * __uint_as_float(hv[e] & 0xffff0000u);
      }
    }
  }
  {
    const int p0 = beg + (nb8 << 3);
    const int cnt = end - p0;
    if (cnt > 0) {
      int svt = 0; float at = 0.f, Svt = 0.f;
      if (ei < cnt) {
        svt = col[p0 + ei];
        at = __expf(lrelu(a_src[svt * HEADS + hh] + adv, 0.2f));
        if (I8H) Svt = hscale[svt];
        if (HEADS == 8 || (lane & 7) == 0) sum += at;
      }
      for (int e = 0; e < cnt; ++e) {
        float al = __shfl(at, e * 8 + bh);
        if (I8H) al *= __shfl(Svt, e * 8);
        const int sx = __shfl(svt, e * 8);
        if (I8H) {
          const int wv = (int)H16[(size_t)sx * 64 + lane];
          accx += al * (float)((wv << 24) >> 24);
          accy += al * (float)((wv << 16) >> 24);
        } else {
          const unsigned int hv = Hu[(size_t)sx * 64 + lane];
          accx += al * __uint_as_float(hv << 16);
          accy += al * __uint_as_float(hv & 0xffff0000u);
        }
      }
    }
  }
  sum += __shfl_xor(sum, 8);
  sum += __shfl_xor(sum, 16);
  sum += __shfl_xor(sum, 32);
  const float denom = __shfl(sum, bh) + 1e-16f;
  const float inv = 1.f / denom;
  agg[(size_t)d * 64 + lane] = (unsigned int)f2bf(accx * inv) | ((unsigned int)f2bf(accy * inv) << 16);
}

// ---------------- h@g + cosine vs mu (bf16 MFMA, 32-node tiles, gm'-tile epilogue) ----------------
__global__ void __launch_bounds__(256)
final_kernel(const unsigned short* __restrict__ agg2b, const float* __restrict__ b2,
             const unsigned short* __restrict__ gt, const unsigned short* __restrict__ gmt,
             float* __restrict__ outp, int n)
{
  __shared__ unsigned short os[32][136];
  const int t = threadIdx.x;
  const int w = t >> 6;
  const int lane = t & 63;
  const int l15 = lane & 15;
  const int lg = lane >> 4;
  const int nbase = blockIdx.x << 5;

  {
    const int r = t >> 3;
    const int c = (t & 7) * 16;
    const int node = nbase + r;
    unsigned short pk[16];
    if (node < n) {
      short8 v0 = *(const short8*)&agg2b[(size_t)node * 128 + c];
      short8 v1 = *(const short8*)&agg2b[(size_t)node * 128 + c + 8];
      #pragma unroll
      for (int j = 0; j < 8; ++j) pk[j]     = f2bf(bf2f((unsigned short)v0[j]) + b2[c + j]);
      #pragma unroll
      for (int j = 0; j < 8; ++j) pk[8 + j] = f2bf(bf2f((unsigned short)v1[j]) + b2[c + 8 + j]);
    } else {
      #pragma unroll
      for (int i = 0; i < 16; ++i) pk[i] = 0;
    }
    *(short8*)&os[r][c]     = *(short8*)&pk[0];
    *(short8*)&os[r][c + 8] = *(short8*)&pk[8];
  }
  __syncthreads();

  short8 afr[2][4];
  #pragma unroll
  for (int rt = 0; rt < 2; ++rt)
    #pragma unroll
    for (int kc = 0; kc < 4; ++kc)
      afr[rt][kc] = *(const short8*)&os[rt * 16 + l15][kc * 32 + lg * 8];

  const unsigned short* gw  = gt  + (size_t)(w * 128 + l15) * 128 + lg * 8;
  const unsigned short* gmw = gmt + (size_t)l15 * 128 + lg * 8;

  f32x4 acc[2][8];
  f32x4 accg[2];
  #pragma unroll
  for (int rt = 0; rt < 2; ++rt) {
    #pragma unroll
    for (int ct = 0; ct < 8; ++ct)
      acc[rt][ct] = (f32x4){0.f, 0.f, 0.f, 0.f};
    accg[rt] = (f32x4){0.f, 0.f, 0.f, 0.f};
  }

  short8 bcur[9], bnxt[9];
  #pragma unroll
  for (int ct = 0; ct < 8; ++ct)
    bcur[ct] = *(const short8*)&gw[(size_t)ct * 2048];
  bcur[8] = *(const short8*)gmw;

  #pragma unroll
  for (int kc = 0; kc < 4; ++kc) {
    if (kc < 3) {
      #pragma unroll
      for (int ct = 0; ct < 8; ++ct)
        bnxt[ct] = *(const short8*)&gw[(size_t)ct * 2048 + (kc + 1) * 32];
      bnxt[8] = *(const short8*)(gmw + (kc + 1) * 32);
    }
    #pragma unroll
    for (int ct = 0; ct < 8; ++ct) {
      acc[0][ct] = __builtin_amdgcn_mfma_f32_16x16x32_bf16(afr[0][kc], bcur[ct], acc[0][ct], 0, 0, 0);
      acc[1][ct] = __builtin_amdgcn_mfma_f32_16x16x32_bf16(afr[1][kc], bcur[ct], acc[1][ct], 0, 0, 0);
    }
    accg[0] = __builtin_amdgcn_mfma_f32_16x16x32_bf16(afr[0][kc], bcur[8], accg[0], 0, 0, 0);
    accg[1] = __builtin_amdgcn_mfma_f32_16x16x32_bf16(afr[1][kc], bcur[8], accg[1], 0, 0, 0);
    if (kc < 3) {
      #pragma unroll
      for (int ct = 0; ct < 9; ++ct) bcur[ct] = bnxt[ct];
    }
  }

  const int k0 = w * 2, k1 = w * 2 + 1;
  #pragma unroll
  for (int rt = 0; rt < 2; ++rt) {
    float ss0[4] = {0.f, 0.f, 0.f, 0.f};
    float ss1[4] = {0.f, 0.f, 0.f, 0.f};
    #pragma unroll
    for (int ct = 0; ct < 4; ++ct) {
      const f32x4 a = acc[rt][ct];
      const f32x4 b = acc[rt][4 + ct];
      #pragma unroll
      for (int r = 0; r < 4; ++r) {
        ss0[r] += a[r] * a[r];
        ss1[r] += b[r] * b[r];
      }
    }
    #pragma unroll
    for (int r = 0; r < 4; ++r) {
      ss0[r] += __shfl_xor(ss0[r], 1); ss1[r] += __shfl_xor(ss1[r], 1);
      ss0[r] += __shfl_xor(ss0[r], 2); ss1[r] += __shfl_xor(ss1[r], 2);
      ss0[r] += __shfl_xor(ss0[r], 4); ss1[r] += __shfl_xor(ss1[r], 4);
      ss0[r] += __shfl_xor(ss0[r], 8); ss1[r] += __shfl_xor(ss1[r], 8);
    }
    #pragma unroll
    for (int r = 0; r < 4; ++r) {
      const int node = nbase + rt * 16 + lg * 4 + r;
      if (node < n) {
        const float nv = accg[rt][r];
        if (l15 == k0)      outp[(size_t)node * 8 + k0] = nv / fmaxf(sqrtf(ss0[r]), 1e-8f);
        else if (l15 == k1) outp[(size_t)node * 8 + k1] = nv / fmaxf(sqrtf(ss1[r]), 1e-8f);
      }
    }
  }
}

extern "C" void kernel_launch(void* const* d_in, const int* in_sizes, int n_in,
                              void* d_out, int out_size, void* d_ws, size_t ws_size,
                              hipStream_t stream)
{
  const float* x   = (const float*)d_in[0];
  const int*   eix = (const int*)d_in[1];
  const float* W1  = (const float*)d_in[2];
  const float* as1 = (const float*)d_in[3];
  const float* ad1 = (const float*)d_in[4];
  const float* b1  = (const float*)d_in[5];
  const float* W2  = (const float*)d_in[6];
  const float* as2 = (const float*)d_in[7];
  const float* ad2 = (const float*)d_in[8];
  const float* b2  = (const float*)d_in[9];
  const float* g   = (const float*)d_in[10];
  const float* mu  = (const float*)d_in[11];
  float* outp = (float*)d_out;

  const int n    = in_sizes[0] / 128;
  const int E    = in_sizes[1] / 2;
  const int* esrc = eix;
  const int* edst = eix + E;

  unsigned short* hb  = (unsigned short*)d_ws;   // H1 int8 (128B/row) or H2 bf16 (256B/row)
  unsigned short* gt  = hb + (size_t)n * 128;
  unsigned short* wt1 = gt + 512 * 128;
  unsigned short* vt1 = wt1 + 128 * 128;
  unsigned short* wt2 = vt1 + 16 * 128;
  unsigned short* vt2 = wt2 + 128 * 128;
  unsigned short* gmt = vt2 + 16 * 128;
  unsigned short* agg_b = (unsigned short*)((char*)d_ws + (size_t)n * 512);
  float* asrc   = (float*)((char*)d_ws + (size_t)n * 1024);
  float* adst   = asrc + (size_t)n * 8;
  int*   rowptr = (int*)(adst + (size_t)n * 8);
  int*   col    = rowptr + n;
  float* hscale = (float*)(col + (size_t)E + n);
  int*   deg    = (int*)agg_b;
  int*   blksum = deg + n;

  // ---------------- deg zero, then fused prep + deg_count ----------------
  hipMemsetAsync(deg, 0, (size_t)n * sizeof(int), stream);
  prep_kernel<<<161 + NSCAT, 256, 0, stream>>>(g, gt, W1, as1, ad1, wt1, vt1,
                                               W2, as2, ad2, wt2, vt2, mu, gmt,
                                               edst, deg, E, n);

  // ---------------- scans ----------------
  const int nb = (n + 2047) / 2048;
  scan1_kernel<<<nb, 256, 0, stream>>>(deg, rowptr, blksum, n);
  scan2_kernel<<<1, 64, 0, stream>>>(blksum, nb);
  scan3_kernel<<<(n + 255) / 256, 256, 0, stream>>>(rowptr, blksum, n);

  // ---------------- fused scatter + feat1 (independent work overlapped) ----------------
  const int nfeat = (n + 63) / 64;
  scatter_feat1_kernel<<<NSCAT + nfeat, 256, 0, stream>>>(
      esrc, edst, rowptr, col, E, x, wt1, vt1, hb, hscale, asrc, adst, n);

  // ---------------- conv1 aggregate (H int8 + per-row scale) ----------------
  agg_csr_kernel<8, true><<<(n + 3) / 4, 256, 0, stream>>>(
      rowptr, col, asrc, adst, hb, hscale, (unsigned int*)agg_b, n);

  // ---------------- conv2 (heads=1, C=128): H in bf16 ----------------
  feat2_kernel<<<nfeat, 256, 0, stream>>>(agg_b, wt2, vt2, b1, hb, asrc, adst, n);
  agg_csr_kernel<1, false><<<(n + 3) / 4, 256, 0, stream>>>(
      rowptr, col, asrc, adst, hb, nullptr, (unsigned int*)agg_b, n);

  // ---------------- h@g + cosine vs mu ----------------
  final_kernel<<<(n + 31) / 32, 256, 0, stream>>>(agg_b, b2, gt, gmt, outp, n);
}